// Round 2
// baseline (19107.477 us; speedup 1.0000x reference)
//
#include <hip/hip_runtime.h>
#include <math.h>

#define LRELU(v) ((v) >= 0.f ? (v) : 0.1f * (v))

// ---------------------------------------------------------------------------
// Fused per-window cross attention: mask + Q/K/V proj + attention + head-mean
// attention output + out-projection + NCHW scatter. One block per 8x8 window,
// 4 waves (one per head).
__global__ __launch_bounds__(256) void fused_attn_kernel(
    const float* __restrict__ ref,   // batch base, [64][H][H]
    const float* __restrict__ ta,    // batch base, [64][H][H]
    const float* __restrict__ qw, const float* __restrict__ qb,
    const float* __restrict__ kw, const float* __restrict__ kb,
    const float* __restrict__ vw, const float* __restrict__ vb,
    const float* __restrict__ pw, const float* __restrict__ pb,
    const float* __restrict__ btab,  // [225][4]
    float* __restrict__ aligned,     // batch base, [64][H][H]
    float* __restrict__ attm,        // [nWin][64][64] head-mean attn, or null
    int H, int nWx)
{
    __shared__ __align__(16) float X[64][68];        // [token][chan] raw ref win (later: O)
    __shared__ __align__(16) float Y[64][68];        // [token][chan] ta win
    __shared__ __align__(16) float Ql[4][64][20];    // [head][token][d]
    __shared__ __align__(16) float Kl[4][64][20];
    __shared__ __align__(16) float Vl[4][64][20];
    __shared__ float AM[64][65];                     // attn head-mean / out staging
    __shared__ float bl[900];
    __shared__ float msk[64];

    const int HW = H * H;
    const int win = blockIdx.x;
    const int wy = win / nWx, wx = win - wy * nWx;
    const int y0 = wy * 8, x0 = wx * 8;
    const int tid = threadIdx.x;

    // stage windows (global: 8x32B segments per wave; LDS write 8-way conflict, cheap)
    for (int r = tid; r < 4096; r += 256) {
        int c = r >> 6, t = r & 63;
        size_t off = (size_t)c * HW + (size_t)(y0 + (t >> 3)) * H + (x0 + (t & 7));
        X[t][c] = ref[off];
        Y[t][c] = ta[off];
    }
    for (int r = tid; r < 900; r += 256) bl[r] = btab[r];
    __syncthreads();

    if (tid < 64) {
        float s = 0.f;
#pragma unroll
        for (int c = 0; c < 64; ++c) s += (X[tid][c] > 0.95f) ? 0.f : 1.f;
        msk[tid] = s * (1.f / 64.f);
    }
    __syncthreads();

    const int h = __builtin_amdgcn_readfirstlane(tid >> 6);
    const int lane = tid & 63;

    // ---- Q/K/V projections: thread computes channel co=lane for 16 tokens of wave h
    {
        float aq[16], ak[16], av[16];
#pragma unroll
        for (int tt = 0; tt < 16; ++tt) { aq[tt] = 0.f; ak[tt] = 0.f; av[tt] = 0.f; }
        const float4* qw4 = reinterpret_cast<const float4*>(qw + lane * 64);
        const float4* kw4 = reinterpret_cast<const float4*>(kw + lane * 64);
        const float4* vw4 = reinterpret_cast<const float4*>(vw + lane * 64);
        for (int c4 = 0; c4 < 16; ++c4) {
            float4 wq = qw4[c4], wk = kw4[c4], wv = vw4[c4];
#pragma unroll
            for (int tt = 0; tt < 16; ++tt) {
                int t = h * 16 + tt;
                float4 xv = *reinterpret_cast<const float4*>(&X[t][c4 * 4]);
                float4 yv = *reinterpret_cast<const float4*>(&Y[t][c4 * 4]);
                aq[tt] += xv.x * wq.x + xv.y * wq.y + xv.z * wq.z + xv.w * wq.w;
                ak[tt] += yv.x * wk.x + yv.y * wk.y + yv.z * wk.z + yv.w * wk.w;
                av[tt] += yv.x * wv.x + yv.y * wv.y + yv.z * wv.z + yv.w * wv.w;
            }
        }
        float qbv = qb[lane], kbv = kb[lane], vbv = vb[lane];
        int co_h = lane >> 4, co_d = lane & 15;
#pragma unroll
        for (int tt = 0; tt < 16; ++tt) {
            int t = h * 16 + tt;
            Ql[co_h][t][co_d] = (aq[tt] * msk[t] + qbv) * 0.25f;  // mask pre-proj, scale post-bias
            Kl[co_h][t][co_d] = ak[tt] + kbv;
            Vl[co_h][t][co_d] = av[tt] + vbv;
        }
    }
    __syncthreads();

    // ---- attention: wave h = head, lane = query token
    float q[16];
#pragma unroll
    for (int d4 = 0; d4 < 4; ++d4) {
        float4 qv = *reinterpret_cast<const float4*>(&Ql[h][lane][d4 * 4]);
        q[d4 * 4 + 0] = qv.x; q[d4 * 4 + 1] = qv.y;
        q[d4 * 4 + 2] = qv.z; q[d4 * 4 + 3] = qv.w;
    }
    const int i1 = lane >> 3, j1 = lane & 7;
    const float mn = msk[lane];
    float p[64];
#pragma unroll
    for (int m = 0; m < 64; ++m) {
        float s = 0.f;
#pragma unroll
        for (int d4 = 0; d4 < 4; ++d4) {
            float4 kv = *reinterpret_cast<const float4*>(&Kl[h][m][d4 * 4]);
            s += q[d4 * 4 + 0] * kv.x + q[d4 * 4 + 1] * kv.y
               + q[d4 * 4 + 2] * kv.z + q[d4 * 4 + 3] * kv.w;
        }
        int bidx = (i1 - (m >> 3) + 7) * 15 + (j1 - (m & 7) + 7);
        p[m] = s * mn * msk[m] + bl[bidx * 4 + h];
    }
    float mx = p[0];
#pragma unroll
    for (int m = 1; m < 64; ++m) mx = fmaxf(mx, p[m]);
    float sum = 0.f;
#pragma unroll
    for (int m = 0; m < 64; ++m) { p[m] = __expf(p[m] - mx); sum += p[m]; }
    float inv = 1.f / sum;
#pragma unroll
    for (int m = 0; m < 64; ++m) p[m] *= inv;

    // ---- head-mean attention (for next-finer level's atttransfer)
    if (attm) {
        for (int turn = 0; turn < 4; ++turn) {
            if (h == turn) {
                if (turn == 0) {
#pragma unroll
                    for (int m = 0; m < 64; ++m) AM[m][lane] = p[m] * 0.25f;
                } else {
#pragma unroll
                    for (int m = 0; m < 64; ++m) AM[m][lane] += p[m] * 0.25f;
                }
            }
            __syncthreads();
        }
        for (int r = tid; r < 4096; r += 256) {
            int t = r >> 6, m = r & 63;
            attm[(size_t)win * 4096 + r] = AM[m][t];
        }
    }

    // ---- PV
    float acc[16];
#pragma unroll
    for (int d = 0; d < 16; ++d) acc[d] = 0.f;
#pragma unroll
    for (int m = 0; m < 64; ++m) {
        float pm = p[m];
#pragma unroll
        for (int d4 = 0; d4 < 4; ++d4) {
            float4 vv = *reinterpret_cast<const float4*>(&Vl[h][m][d4 * 4]);
            acc[d4 * 4 + 0] += pm * vv.x; acc[d4 * 4 + 1] += pm * vv.y;
            acc[d4 * 4 + 2] += pm * vv.z; acc[d4 * 4 + 3] += pm * vv.w;
        }
    }
    // stage O into X (X free after projections): O[token][chan]
#pragma unroll
    for (int d = 0; d < 16; ++d) X[lane][h * 16 + d] = acc[d];
    __syncthreads();

    // ---- output projection: thread computes channel co=lane for 16 tokens of wave h
    {
        float o[16];
        float pbv = pb[lane];
#pragma unroll
        for (int tt = 0; tt < 16; ++tt) o[tt] = pbv;
        const float4* pw4 = reinterpret_cast<const float4*>(pw + lane * 64);
        for (int c4 = 0; c4 < 16; ++c4) {
            float4 w = pw4[c4];
#pragma unroll
            for (int tt = 0; tt < 16; ++tt) {
                int t = h * 16 + tt;
                float4 ov = *reinterpret_cast<const float4*>(&X[t][c4 * 4]);
                o[tt] += ov.x * w.x + ov.y * w.y + ov.z * w.z + ov.w * w.w;
            }
        }
#pragma unroll
        for (int tt = 0; tt < 16; ++tt) AM[lane][h * 16 + tt] = o[tt];
    }
    __syncthreads();
    // scatter to NCHW (8x32B segments per wave)
    for (int r = tid; r < 4096; r += 256) {
        int c = r >> 6, t = r & 63;
        aligned[(size_t)c * HW + (size_t)(y0 + (t >> 3)) * H + (x0 + (t & 7))] = AM[c][t];
    }
}

// ---------------------------------------------------------------------------
// atrans[c,Y,X] = sum_{mi,mj} attm[win, t(Y,X), mi*8+mj] * ta[c, wh*16+2mi+pi, ww*16+2mj+pj]
// per-batch version.
__global__ __launch_bounds__(256) void atttrans_kernel(const float* __restrict__ ta,
                                                       const float* __restrict__ attm,
                                                       float* __restrict__ out,
                                                       int H, int HW, int nWx16, int total) {
    int idx = blockIdx.x * 256 + threadIdx.x;
    if (idx >= total) return;
    int X = idx % H;
    int r1 = idx / H;
    int Y = r1 % H;
    int c = r1 / H;
    int wh = Y >> 4, ww = X >> 4;
    int win = wh * nWx16 + ww;
    int t = ((Y & 15) >> 1) * 8 + ((X & 15) >> 1);
    const float* ap = attm + ((size_t)win * 64 + t) * 64;
    const float* tp = ta + (size_t)c * HW
                         + (size_t)((wh << 4) + (Y & 1)) * H + (ww << 4) + (X & 1);
    float acc = 0.f;
#pragma unroll
    for (int mi = 0; mi < 8; ++mi) {
#pragma unroll
        for (int mj = 0; mj < 8; ++mj)
            acc = fmaf(ap[mi * 8 + mj], tp[(size_t)(mi * 2) * H + mj * 2], acc);
    }
    out[idx] = acc;
}

// ---------------------------------------------------------------------------
// 3x3 SAME conv, 192->64 channels, 3 separate 64-ch inputs. Per-batch.
__global__ __launch_bounds__(64) void conv_kernel(const float* __restrict__ s0,
                                                  const float* __restrict__ s1,
                                                  const float* __restrict__ s2,
                                                  const float* __restrict__ w,
                                                  const float* __restrict__ bias,
                                                  float* __restrict__ out,
                                                  int H, int HW, int apply_lrelu) {
    int x = blockIdx.x * 64 + threadIdx.x;
    int y = blockIdx.y;
    int co = blockIdx.z;
    float acc = bias[co];
    const float* wco = w + (size_t)co * 192 * 9;
    for (int s = 0; s < 3; ++s) {
        const float* src = (s == 0 ? s0 : (s == 1 ? s1 : s2));
        const float* wsrc = wco + s * 64 * 9;
        for (int ci = 0; ci < 64; ++ci) {
            const float* sp = src + (size_t)ci * HW;
            const float* wp = wsrc + ci * 9;
#pragma unroll
            for (int ky = 0; ky < 3; ++ky) {
                int yy = y + ky - 1;
                if (yy < 0 || yy >= H) continue;
                const float* row = sp + (size_t)yy * H;
                float w0 = wp[ky * 3 + 0], w1 = wp[ky * 3 + 1], w2 = wp[ky * 3 + 2];
                if (x > 0) acc = fmaf(row[x - 1], w0, acc);
                acc = fmaf(row[x], w1, acc);
                if (x < H - 1) acc = fmaf(row[x + 1], w2, acc);
            }
        }
    }
    if (apply_lrelu) acc = LRELU(acc);
    out[(size_t)co * HW + (size_t)y * H + x] = acc;
}

// ---------------------------------------------------------------------------
// 2x bilinear upsample of lrelu(in); jax.image.resize linear semantics
// (src=(dst+0.5)/2-0.5 -> weights 0.75/0.25, edge clamp == renormalize). Per-batch.
__global__ __launch_bounds__(256) void upsample_kernel(const float* __restrict__ in,
                                                       float* __restrict__ out,
                                                       int Hin, int total) {
    int idx = blockIdx.x * 256 + threadIdx.x;
    if (idx >= total) return;
    int W2 = Hin * 2;
    int X = idx % W2;
    int r1 = idx / W2;
    int Y = r1 % W2;
    int c = r1 / W2;
    int y0 = Y >> 1, x0 = X >> 1;
    int ya = (Y & 1) ? y0 + 1 : y0 - 1;
    int xa = (X & 1) ? x0 + 1 : x0 - 1;
    ya = ya < 0 ? 0 : (ya >= Hin ? Hin - 1 : ya);
    xa = xa < 0 ? 0 : (xa >= Hin ? Hin - 1 : xa);
    const float* pbase = in + (size_t)c * Hin * Hin;
    float v00 = LRELU(pbase[(size_t)y0 * Hin + x0]);
    float v01 = LRELU(pbase[(size_t)y0 * Hin + xa]);
    float v10 = LRELU(pbase[(size_t)ya * Hin + x0]);
    float v11 = LRELU(pbase[(size_t)ya * Hin + xa]);
    out[idx] = 0.5625f * v00 + 0.1875f * (v01 + v10) + 0.0625f * v11;
}

// ---------------------------------------------------------------------------
extern "C" void kernel_launch(void* const* d_in, const int* in_sizes, int n_in,
                              void* d_out, int out_size, void* d_ws, size_t ws_size,
                              hipStream_t stream) {
    const float* refs[3] = { (const float*)d_in[0], (const float*)d_in[1], (const float*)d_in[2] };
    const float* tas[3]  = { (const float*)d_in[3], (const float*)d_in[4], (const float*)d_in[5] };
    const float* q_w = (const float*)d_in[6];
    const float* q_b = (const float*)d_in[7];
    const float* k_w = (const float*)d_in[8];
    const float* k_b = (const float*)d_in[9];
    const float* v_w = (const float*)d_in[10];
    const float* v_b = (const float*)d_in[11];
    const float* p_w = (const float*)d_in[12];
    const float* p_b = (const float*)d_in[13];
    const float* btab = (const float*)d_in[14];
    const float* fc_w = (const float*)d_in[15];
    const float* fc_b = (const float*)d_in[16];

    // per-batch scratch (reused across batches): ~60 MB total
    float* ws = (float*)d_ws;
    float* ALIGNED = ws;                  // 4,194,304 floats (64 x 256 x 256)
    float* ATRANS  = ws + 4194304;        // 4,194,304
    float* UPS     = ws + 8388608;        // 4,194,304
    float* FEAT2   = ws + 12582912;       // 1,048,576 (64 x 128 x 128)
    float* ATTMA   = ws + 13631488;       //   262,144 (64 win x 64 x 64)
    float* ATTMB   = ws + 13893632;       // 1,048,576 (256 win x 64 x 64)

    const int Hs[3] = { 256, 128, 64 };
    for (int b = 0; b < 4; ++b) {
        for (int j = 2; j >= 0; --j) {
            int H = Hs[j];
            int HW = H * H;
            int nWx = H / 8;
            int nWin = nWx * nWx;
            const float* ref_b = refs[j] + (size_t)b * 64 * HW;
            const float* ta_b  = tas[j]  + (size_t)b * 64 * HW;
            float* attm_out = (j == 2) ? ATTMA : ((j == 1) ? ATTMB : nullptr);

            fused_attn_kernel<<<nWin, 256, 0, stream>>>(
                ref_b, ta_b,
                q_w + j * 4096, q_b + j * 64, k_w + j * 4096, k_b + j * 64,
                v_w + j * 4096, v_b + j * 64, p_w + j * 4096, p_b + j * 64,
                btab + j * 900, ALIGNED, attm_out, H, nWx);

            if (j < 2) {
                const float* attm_in = (j == 1) ? ATTMA : ATTMB;  // coarser level's attn
                atttrans_kernel<<<(64 * HW) / 256, 256, 0, stream>>>(
                    ta_b, attm_in, ATRANS, H, HW, H / 16, 64 * HW);
                conv_kernel<<<dim3(H / 64, H, 64), 64, 0, stream>>>(
                    ALIGNED, UPS, ATRANS, fc_w + (size_t)j * 110592, fc_b + j * 64,
                    j == 0 ? ((float*)d_out + (size_t)b * 64 * HW) : FEAT2,
                    H, HW, j == 0 ? 1 : 0);
            }
            if (j > 0) {
                const float* upin = (j == 2) ? ALIGNED : FEAT2;   // lrelu applied in-kernel
                upsample_kernel<<<(64 * 4 * HW) / 256, 256, 0, stream>>>(
                    upin, UPS, H, 64 * 4 * HW);
            }
        }
    }
}

// Round 3
// 6137.022 us; speedup vs baseline: 3.1135x; 3.1135x over previous
//
#include <hip/hip_runtime.h>
#include <math.h>

#define LRELU(v) ((v) >= 0.f ? (v) : 0.1f * (v))

// ---------------------------------------------------------------------------
// Fused per-window cross attention: mask + Q/K/V proj + attention + head-mean
// attention output + out-projection + NCHW scatter. One block per 8x8 window,
// 4 waves (one per head).
__global__ __launch_bounds__(256) void fused_attn_kernel(
    const float* __restrict__ ref,   // batch base, [64][H][H]
    const float* __restrict__ ta,    // batch base, [64][H][H]
    const float* __restrict__ qw, const float* __restrict__ qb,
    const float* __restrict__ kw, const float* __restrict__ kb,
    const float* __restrict__ vw, const float* __restrict__ vb,
    const float* __restrict__ pw, const float* __restrict__ pb,
    const float* __restrict__ btab,  // [225][4]
    float* __restrict__ aligned,     // batch base, [64][H][H]
    float* __restrict__ attm,        // [nWin][64][64] head-mean attn, or null
    int H, int nWx)
{
    __shared__ __align__(16) float X[64][68];        // [token][chan] raw ref win (later: O)
    __shared__ __align__(16) float Y[64][68];        // [token][chan] ta win
    __shared__ __align__(16) float Ql[4][64][20];    // [head][token][d]
    __shared__ __align__(16) float Kl[4][64][20];
    __shared__ __align__(16) float Vl[4][64][20];
    __shared__ float AM[64][65];                     // attn head-mean / out staging
    __shared__ float bl[900];
    __shared__ float msk[64];

    const int HW = H * H;
    const int win = blockIdx.x;
    const int wy = win / nWx, wx = win - wy * nWx;
    const int y0 = wy * 8, x0 = wx * 8;
    const int tid = threadIdx.x;

    // stage windows (global: 8x32B segments per wave; LDS write 8-way conflict, cheap)
    for (int r = tid; r < 4096; r += 256) {
        int c = r >> 6, t = r & 63;
        size_t off = (size_t)c * HW + (size_t)(y0 + (t >> 3)) * H + (x0 + (t & 7));
        X[t][c] = ref[off];
        Y[t][c] = ta[off];
    }
    for (int r = tid; r < 900; r += 256) bl[r] = btab[r];
    __syncthreads();

    if (tid < 64) {
        float s = 0.f;
#pragma unroll
        for (int c = 0; c < 64; ++c) s += (X[tid][c] > 0.95f) ? 0.f : 1.f;
        msk[tid] = s * (1.f / 64.f);
    }
    __syncthreads();

    const int h = __builtin_amdgcn_readfirstlane(tid >> 6);
    const int lane = tid & 63;

    // ---- Q/K/V projections: thread computes channel co=lane for 16 tokens of wave h
    {
        float aq[16], ak[16], av[16];
#pragma unroll
        for (int tt = 0; tt < 16; ++tt) { aq[tt] = 0.f; ak[tt] = 0.f; av[tt] = 0.f; }
        const float4* qw4 = reinterpret_cast<const float4*>(qw + lane * 64);
        const float4* kw4 = reinterpret_cast<const float4*>(kw + lane * 64);
        const float4* vw4 = reinterpret_cast<const float4*>(vw + lane * 64);
        for (int c4 = 0; c4 < 16; ++c4) {
            float4 wq = qw4[c4], wk = kw4[c4], wv = vw4[c4];
#pragma unroll
            for (int tt = 0; tt < 16; ++tt) {
                int t = h * 16 + tt;
                float4 xv = *reinterpret_cast<const float4*>(&X[t][c4 * 4]);
                float4 yv = *reinterpret_cast<const float4*>(&Y[t][c4 * 4]);
                aq[tt] += xv.x * wq.x + xv.y * wq.y + xv.z * wq.z + xv.w * wq.w;
                ak[tt] += yv.x * wk.x + yv.y * wk.y + yv.z * wk.z + yv.w * wk.w;
                av[tt] += yv.x * wv.x + yv.y * wv.y + yv.z * wv.z + yv.w * wv.w;
            }
        }
        float qbv = qb[lane], kbv = kb[lane], vbv = vb[lane];
        int co_h = lane >> 4, co_d = lane & 15;
#pragma unroll
        for (int tt = 0; tt < 16; ++tt) {
            int t = h * 16 + tt;
            Ql[co_h][t][co_d] = (aq[tt] * msk[t] + qbv) * 0.25f;  // mask pre-proj, scale post-bias
            Kl[co_h][t][co_d] = ak[tt] + kbv;
            Vl[co_h][t][co_d] = av[tt] + vbv;
        }
    }
    __syncthreads();

    // ---- attention: wave h = head, lane = query token
    float q[16];
#pragma unroll
    for (int d4 = 0; d4 < 4; ++d4) {
        float4 qv = *reinterpret_cast<const float4*>(&Ql[h][lane][d4 * 4]);
        q[d4 * 4 + 0] = qv.x; q[d4 * 4 + 1] = qv.y;
        q[d4 * 4 + 2] = qv.z; q[d4 * 4 + 3] = qv.w;
    }
    const int i1 = lane >> 3, j1 = lane & 7;
    const float mn = msk[lane];
    float p[64];
#pragma unroll
    for (int m = 0; m < 64; ++m) {
        float s = 0.f;
#pragma unroll
        for (int d4 = 0; d4 < 4; ++d4) {
            float4 kv = *reinterpret_cast<const float4*>(&Kl[h][m][d4 * 4]);
            s += q[d4 * 4 + 0] * kv.x + q[d4 * 4 + 1] * kv.y
               + q[d4 * 4 + 2] * kv.z + q[d4 * 4 + 3] * kv.w;
        }
        int bidx = (i1 - (m >> 3) + 7) * 15 + (j1 - (m & 7) + 7);
        p[m] = s * mn * msk[m] + bl[bidx * 4 + h];
    }
    float mx = p[0];
#pragma unroll
    for (int m = 1; m < 64; ++m) mx = fmaxf(mx, p[m]);
    float sum = 0.f;
#pragma unroll
    for (int m = 0; m < 64; ++m) { p[m] = __expf(p[m] - mx); sum += p[m]; }
    float inv = 1.f / sum;
#pragma unroll
    for (int m = 0; m < 64; ++m) p[m] *= inv;

    // ---- head-mean attention (for next-finer level's atttransfer)
    if (attm) {
        for (int turn = 0; turn < 4; ++turn) {
            if (h == turn) {
                if (turn == 0) {
#pragma unroll
                    for (int m = 0; m < 64; ++m) AM[m][lane] = p[m] * 0.25f;
                } else {
#pragma unroll
                    for (int m = 0; m < 64; ++m) AM[m][lane] += p[m] * 0.25f;
                }
            }
            __syncthreads();
        }
        for (int r = tid; r < 4096; r += 256) {
            int t = r >> 6, m = r & 63;
            attm[(size_t)win * 4096 + r] = AM[m][t];
        }
    }

    // ---- PV
    float acc[16];
#pragma unroll
    for (int d = 0; d < 16; ++d) acc[d] = 0.f;
#pragma unroll
    for (int m = 0; m < 64; ++m) {
        float pm = p[m];
#pragma unroll
        for (int d4 = 0; d4 < 4; ++d4) {
            float4 vv = *reinterpret_cast<const float4*>(&Vl[h][m][d4 * 4]);
            acc[d4 * 4 + 0] += pm * vv.x; acc[d4 * 4 + 1] += pm * vv.y;
            acc[d4 * 4 + 2] += pm * vv.z; acc[d4 * 4 + 3] += pm * vv.w;
        }
    }
    // stage O into X (X free after projections): O[token][chan]
#pragma unroll
    for (int d = 0; d < 16; ++d) X[lane][h * 16 + d] = acc[d];
    __syncthreads();

    // ---- output projection: thread computes channel co=lane for 16 tokens of wave h
    {
        float o[16];
        float pbv = pb[lane];
#pragma unroll
        for (int tt = 0; tt < 16; ++tt) o[tt] = pbv;
        const float4* pw4 = reinterpret_cast<const float4*>(pw + lane * 64);
        for (int c4 = 0; c4 < 16; ++c4) {
            float4 w = pw4[c4];
#pragma unroll
            for (int tt = 0; tt < 16; ++tt) {
                int t = h * 16 + tt;
                float4 ov = *reinterpret_cast<const float4*>(&X[t][c4 * 4]);
                o[tt] += ov.x * w.x + ov.y * w.y + ov.z * w.z + ov.w * w.w;
            }
        }
#pragma unroll
        for (int tt = 0; tt < 16; ++tt) AM[lane][h * 16 + tt] = o[tt];
    }
    __syncthreads();
    // scatter to NCHW (8x32B segments per wave)
    for (int r = tid; r < 4096; r += 256) {
        int c = r >> 6, t = r & 63;
        aligned[(size_t)c * HW + (size_t)(y0 + (t >> 3)) * H + (x0 + (t & 7))] = AM[c][t];
    }
}

// ---------------------------------------------------------------------------
// atrans[c,Y,X] = sum_{mi,mj} attm[win, t(Y,X), mi*8+mj] * ta[c, wh*16+2mi+pi, ww*16+2mj+pj]
__global__ __launch_bounds__(256) void atttrans_kernel(const float* __restrict__ ta,
                                                       const float* __restrict__ attm,
                                                       float* __restrict__ out,
                                                       int H, int HW, int nWx16, int total) {
    int idx = blockIdx.x * 256 + threadIdx.x;
    if (idx >= total) return;
    int X = idx % H;
    int r1 = idx / H;
    int Y = r1 % H;
    int c = r1 / H;
    int wh = Y >> 4, ww = X >> 4;
    int win = wh * nWx16 + ww;
    int t = ((Y & 15) >> 1) * 8 + ((X & 15) >> 1);
    const float* ap = attm + ((size_t)win * 64 + t) * 64;
    const float* tp = ta + (size_t)c * HW
                         + (size_t)((wh << 4) + (Y & 1)) * H + (ww << 4) + (X & 1);
    float acc = 0.f;
#pragma unroll
    for (int mi = 0; mi < 8; ++mi) {
#pragma unroll
        for (int mj = 0; mj < 8; ++mj)
            acc = fmaf(ap[mi * 8 + mj], tp[(size_t)(mi * 2) * H + mj * 2], acc);
    }
    out[idx] = acc;
}

// ---------------------------------------------------------------------------
// Weight transform for tiled conv: Wt[((ci*3+ky)*3+kx)*64 + co] = fc_w[co][ci][ky][kx]
__global__ __launch_bounds__(256) void wtrans_kernel(const float* __restrict__ src,
                                                     float* __restrict__ dst) {
    int idx = blockIdx.x * 256 + threadIdx.x;   // 110592 total
    int co = idx & 63;
    int rest = idx >> 6;
    int kx = rest % 3;
    int r2 = rest / 3;
    int ky = r2 % 3;
    int ci = r2 / 3;
    dst[idx] = src[((co * 192 + ci) * 3 + ky) * 3 + kx];
}

// ---------------------------------------------------------------------------
// Tiled 3x3 SAME conv, 192->64 ch. Block = [64 co][4 y][64 x] output tile,
// 256 threads: wave = one y row, lane = (co_g = l>>3)*8 channels x (x_g = l&7)*8 px.
// Input rows double-buffered in LDS (8 ci per chunk), weights from L1 (Wt layout).
__global__ __launch_bounds__(256) void conv_tiled_kernel(
    const float* __restrict__ s0, const float* __restrict__ s1,
    const float* __restrict__ s2,
    const float* __restrict__ Wt,     // [576][3][64]
    const float* __restrict__ bias,
    float* __restrict__ out,
    int H, int HW, int apply_lrelu)
{
    __shared__ __align__(16) float Bl[2][8][6][68];

    const int tid = threadIdx.x;
    const int lane = tid & 63;
    const int wv = __builtin_amdgcn_readfirstlane(tid >> 6);  // y offset in tile
    const int co_base = (lane >> 3) * 8;
    const int xb = (lane & 7) * 8;
    const int x0 = blockIdx.x * 64;
    const int y0 = blockIdx.y * 4;

    float acc[8][8];
#pragma unroll
    for (int cc = 0; cc < 8; ++cc)
#pragma unroll
        for (int xx = 0; xx < 8; ++xx) acc[cc][xx] = 0.f;

    // staging work split: 768 aligned float4 slots (3/thread) + 96 halo scalars
    const int seg0 = tid, seg1 = tid + 256, seg2 = tid + 512;
    float4 st[3];
    float sth = 0.f;
    const int hseg = tid >> 1, hside = tid & 1;
    const int hx = hside ? (x0 + 64) : (x0 - 1);

    auto stage_load = [&](int cbase) {
        const int slots[3] = { seg0, seg1, seg2 };
#pragma unroll
        for (int s = 0; s < 3; ++s) {
            int slot = slots[s];
            int seg = slot >> 4, f4 = slot & 15;
            int ci_l = seg / 6, r = seg % 6;
            int ci = cbase + ci_l;
            int y_src = y0 - 1 + r;
            const float* src = (ci < 64) ? s0 : ((ci < 128) ? s1 : s2);
            int cloc = ci & 63;
            if (y_src >= 0 && y_src < H) {
                st[s] = *reinterpret_cast<const float4*>(
                    src + (size_t)cloc * HW + (size_t)y_src * H + x0 + f4 * 4);
            } else {
                st[s] = make_float4(0.f, 0.f, 0.f, 0.f);
            }
        }
        if (tid < 96) {
            int ci = cbase + hseg / 6;
            int r = hseg % 6;
            int y_src = y0 - 1 + r;
            const float* src = (ci < 64) ? s0 : ((ci < 128) ? s1 : s2);
            int cloc = ci & 63;
            sth = (y_src >= 0 && y_src < H && hx >= 0 && hx < H)
                      ? src[(size_t)cloc * HW + (size_t)y_src * H + hx] : 0.f;
        }
    };
    auto stage_write = [&](int buf) {
        const int slots[3] = { seg0, seg1, seg2 };
#pragma unroll
        for (int s = 0; s < 3; ++s) {
            int slot = slots[s];
            int seg = slot >> 4, f4 = slot & 15;
            int ci_l = seg / 6, r = seg % 6;
            float* dp = &Bl[buf][ci_l][r][1 + f4 * 4];
            dp[0] = st[s].x; dp[1] = st[s].y; dp[2] = st[s].z; dp[3] = st[s].w;
        }
        if (tid < 96) {
            Bl[buf][hseg / 6][hseg % 6][hside ? 65 : 0] = sth;
        }
    };

    stage_load(0);
    stage_write(0);
    __syncthreads();

    for (int c = 0; c < 24; ++c) {
        int buf = c & 1;
        if (c < 23) stage_load((c + 1) * 8);   // issue VMEM early; lands under compute
        int cbase = c * 8;
        for (int ci_l = 0; ci_l < 8; ++ci_l) {
#pragma unroll
            for (int ky = 0; ky < 3; ++ky) {
                int k = (cbase + ci_l) * 3 + ky;
                const float4* wp = reinterpret_cast<const float4*>(
                    Wt + (size_t)k * 192 + co_base);
                float4 a0 = wp[0], a1 = wp[1];      // kx=0
                float4 a2 = wp[16], a3 = wp[17];    // kx=1
                float4 a4 = wp[32], a5 = wp[33];    // kx=2
                const float4* bp = reinterpret_cast<const float4*>(
                    &Bl[buf][ci_l][wv + ky][xb]);
                float4 b0 = bp[0], b1 = bp[1], b2 = bp[2];
                float bv[12] = { b0.x, b0.y, b0.z, b0.w, b1.x, b1.y, b1.z, b1.w,
                                 b2.x, b2.y, b2.z, b2.w };
                float av[3][8] = {
                    { a0.x, a0.y, a0.z, a0.w, a1.x, a1.y, a1.z, a1.w },
                    { a2.x, a2.y, a2.z, a2.w, a3.x, a3.y, a3.z, a3.w },
                    { a4.x, a4.y, a4.z, a4.w, a5.x, a5.y, a5.z, a5.w } };
#pragma unroll
                for (int xx = 0; xx < 8; ++xx) {
#pragma unroll
                    for (int kx = 0; kx < 3; ++kx) {
                        float b = bv[xx + kx];
#pragma unroll
                        for (int cc = 0; cc < 8; ++cc)
                            acc[cc][xx] = fmaf(av[kx][cc], b, acc[cc][xx]);
                    }
                }
            }
        }
        if (c < 23) {
            __syncthreads();
            stage_write(buf ^ 1);
            __syncthreads();
        }
    }

    // epilogue: bias (+ optional lrelu), coalesced float4 stores
    float bv8[8];
#pragma unroll
    for (int cc = 0; cc < 8; ++cc) bv8[cc] = bias[co_base + cc];
    const int y = y0 + wv;
#pragma unroll
    for (int cc = 0; cc < 8; ++cc) {
        float o[8];
#pragma unroll
        for (int xx = 0; xx < 8; ++xx) {
            float v = acc[cc][xx] + bv8[cc];
            o[xx] = apply_lrelu ? LRELU(v) : v;
        }
        float* op = out + (size_t)(co_base + cc) * HW + (size_t)y * H + x0 + xb;
        *reinterpret_cast<float4*>(op) = make_float4(o[0], o[1], o[2], o[3]);
        *reinterpret_cast<float4*>(op + 4) = make_float4(o[4], o[5], o[6], o[7]);
    }
}

// ---------------------------------------------------------------------------
// 2x bilinear upsample of lrelu(in); jax.image.resize linear semantics.
__global__ __launch_bounds__(256) void upsample_kernel(const float* __restrict__ in,
                                                       float* __restrict__ out,
                                                       int Hin, int total) {
    int idx = blockIdx.x * 256 + threadIdx.x;
    if (idx >= total) return;
    int W2 = Hin * 2;
    int X = idx % W2;
    int r1 = idx / W2;
    int Y = r1 % W2;
    int c = r1 / W2;
    int y0 = Y >> 1, x0 = X >> 1;
    int ya = (Y & 1) ? y0 + 1 : y0 - 1;
    int xa = (X & 1) ? x0 + 1 : x0 - 1;
    ya = ya < 0 ? 0 : (ya >= Hin ? Hin - 1 : ya);
    xa = xa < 0 ? 0 : (xa >= Hin ? Hin - 1 : xa);
    const float* pbase = in + (size_t)c * Hin * Hin;
    float v00 = LRELU(pbase[(size_t)y0 * Hin + x0]);
    float v01 = LRELU(pbase[(size_t)y0 * Hin + xa]);
    float v10 = LRELU(pbase[(size_t)ya * Hin + x0]);
    float v11 = LRELU(pbase[(size_t)ya * Hin + xa]);
    out[idx] = 0.5625f * v00 + 0.1875f * (v01 + v10) + 0.0625f * v11;
}

// ---------------------------------------------------------------------------
extern "C" void kernel_launch(void* const* d_in, const int* in_sizes, int n_in,
                              void* d_out, int out_size, void* d_ws, size_t ws_size,
                              hipStream_t stream) {
    const float* refs[3] = { (const float*)d_in[0], (const float*)d_in[1], (const float*)d_in[2] };
    const float* tas[3]  = { (const float*)d_in[3], (const float*)d_in[4], (const float*)d_in[5] };
    const float* q_w = (const float*)d_in[6];
    const float* q_b = (const float*)d_in[7];
    const float* k_w = (const float*)d_in[8];
    const float* k_b = (const float*)d_in[9];
    const float* v_w = (const float*)d_in[10];
    const float* v_b = (const float*)d_in[11];
    const float* p_w = (const float*)d_in[12];
    const float* p_b = (const float*)d_in[13];
    const float* btab = (const float*)d_in[14];
    const float* fc_w = (const float*)d_in[15];
    const float* fc_b = (const float*)d_in[16];

    // per-batch scratch (reused across batches): ~61 MB total
    float* ws = (float*)d_ws;
    float* ALIGNED = ws;                  // 4,194,304 floats (64 x 256 x 256)
    float* ATRANS  = ws + 4194304;        // 4,194,304
    float* UPS     = ws + 8388608;        // 4,194,304
    float* FEAT2   = ws + 12582912;       // 1,048,576 (64 x 128 x 128)
    float* ATTMA   = ws + 13631488;       //   262,144 (64 win x 64 x 64)
    float* ATTMB   = ws + 13893632;       // 1,048,576 (256 win x 64 x 64)
    float* WT0     = ws + 14942208;       //   110,592 (transformed fc_w[0])
    float* WT1     = ws + 15052800;       //   110,592 (transformed fc_w[1])

    // one-time weight transforms (before batch loop)
    wtrans_kernel<<<432, 256, 0, stream>>>(fc_w, WT0);
    wtrans_kernel<<<432, 256, 0, stream>>>(fc_w + 110592, WT1);

    const int Hs[3] = { 256, 128, 64 };
    for (int b = 0; b < 4; ++b) {
        for (int j = 2; j >= 0; --j) {
            int H = Hs[j];
            int HW = H * H;
            int nWx = H / 8;
            int nWin = nWx * nWx;
            const float* ref_b = refs[j] + (size_t)b * 64 * HW;
            const float* ta_b  = tas[j]  + (size_t)b * 64 * HW;
            float* attm_out = (j == 2) ? ATTMA : ((j == 1) ? ATTMB : nullptr);

            fused_attn_kernel<<<nWin, 256, 0, stream>>>(
                ref_b, ta_b,
                q_w + j * 4096, q_b + j * 64, k_w + j * 4096, k_b + j * 64,
                v_w + j * 4096, v_b + j * 64, p_w + j * 4096, p_b + j * 64,
                btab + j * 900, ALIGNED, attm_out, H, nWx);

            if (j < 2) {
                const float* attm_in = (j == 1) ? ATTMA : ATTMB;  // coarser level's attn
                atttrans_kernel<<<(64 * HW) / 256, 256, 0, stream>>>(
                    ta_b, attm_in, ATRANS, H, HW, H / 16, 64 * HW);
                conv_tiled_kernel<<<dim3(H / 64, H / 4), 256, 0, stream>>>(
                    ALIGNED, UPS, ATRANS, (j == 0) ? WT0 : WT1, fc_b + j * 64,
                    j == 0 ? ((float*)d_out + (size_t)b * 64 * HW) : FEAT2,
                    H, HW, j == 0 ? 1 : 0);
            }
            if (j > 0) {
                const float* upin = (j == 2) ? ALIGNED : FEAT2;   // lrelu applied in-kernel
                upsample_kernel<<<(64 * 4 * HW) / 256, 256, 0, stream>>>(
                    upin, UPS, H, 64 * 4 * HW);
            }
        }
    }
}

// Round 4
// 4304.821 us; speedup vs baseline: 4.4386x; 1.4256x over previous
//
#include <hip/hip_runtime.h>
#include <math.h>

#define LRELU(v) ((v) >= 0.f ? (v) : 0.1f * (v))

// ---------------------------------------------------------------------------
// Fused per-window cross attention: mask + Q/K/V proj + attention + head-mean
// attention output + out-projection + NCHW scatter. One block per 8x8 window,
// 4 waves (one per head).
__global__ __launch_bounds__(256) void fused_attn_kernel(
    const float* __restrict__ ref,   // batch base, [64][H][H]
    const float* __restrict__ ta,    // batch base, [64][H][H]
    const float* __restrict__ qw, const float* __restrict__ qb,
    const float* __restrict__ kw, const float* __restrict__ kb,
    const float* __restrict__ vw, const float* __restrict__ vb,
    const float* __restrict__ pw, const float* __restrict__ pb,
    const float* __restrict__ btab,  // [225][4]
    float* __restrict__ aligned,     // batch base, [64][H][H]
    float* __restrict__ attm,        // [nWin][64][64] head-mean attn, or null
    int H, int nWx)
{
    __shared__ __align__(16) float X[64][68];        // [token][chan] raw ref win (later: O)
    __shared__ __align__(16) float Y[64][68];        // [token][chan] ta win
    __shared__ __align__(16) float Ql[4][64][20];    // [head][token][d]
    __shared__ __align__(16) float Kl[4][64][20];
    __shared__ __align__(16) float Vl[4][64][20];
    __shared__ float AM[64][65];                     // attn head-mean / out staging
    __shared__ float bl[900];
    __shared__ float msk[64];

    const int HW = H * H;
    const int win = blockIdx.x;
    const int wy = win / nWx, wx = win - wy * nWx;
    const int y0 = wy * 8, x0 = wx * 8;
    const int tid = threadIdx.x;

    // stage windows (global: 8x32B segments per wave; LDS write 8-way conflict, cheap)
    for (int r = tid; r < 4096; r += 256) {
        int c = r >> 6, t = r & 63;
        size_t off = (size_t)c * HW + (size_t)(y0 + (t >> 3)) * H + (x0 + (t & 7));
        X[t][c] = ref[off];
        Y[t][c] = ta[off];
    }
    for (int r = tid; r < 900; r += 256) bl[r] = btab[r];
    __syncthreads();

    if (tid < 64) {
        float s = 0.f;
#pragma unroll
        for (int c = 0; c < 64; ++c) s += (X[tid][c] > 0.95f) ? 0.f : 1.f;
        msk[tid] = s * (1.f / 64.f);
    }
    __syncthreads();

    const int h = __builtin_amdgcn_readfirstlane(tid >> 6);
    const int lane = tid & 63;

    // ---- Q/K/V projections: thread computes channel co=lane for 16 tokens of wave h
    {
        float aq[16], ak[16], av[16];
#pragma unroll
        for (int tt = 0; tt < 16; ++tt) { aq[tt] = 0.f; ak[tt] = 0.f; av[tt] = 0.f; }
        const float4* qw4 = reinterpret_cast<const float4*>(qw + lane * 64);
        const float4* kw4 = reinterpret_cast<const float4*>(kw + lane * 64);
        const float4* vw4 = reinterpret_cast<const float4*>(vw + lane * 64);
        for (int c4 = 0; c4 < 16; ++c4) {
            float4 wq = qw4[c4], wk = kw4[c4], wv = vw4[c4];
#pragma unroll
            for (int tt = 0; tt < 16; ++tt) {
                int t = h * 16 + tt;
                float4 xv = *reinterpret_cast<const float4*>(&X[t][c4 * 4]);
                float4 yv = *reinterpret_cast<const float4*>(&Y[t][c4 * 4]);
                aq[tt] += xv.x * wq.x + xv.y * wq.y + xv.z * wq.z + xv.w * wq.w;
                ak[tt] += yv.x * wk.x + yv.y * wk.y + yv.z * wk.z + yv.w * wk.w;
                av[tt] += yv.x * wv.x + yv.y * wv.y + yv.z * wv.z + yv.w * wv.w;
            }
        }
        float qbv = qb[lane], kbv = kb[lane], vbv = vb[lane];
        int co_h = lane >> 4, co_d = lane & 15;
#pragma unroll
        for (int tt = 0; tt < 16; ++tt) {
            int t = h * 16 + tt;
            Ql[co_h][t][co_d] = (aq[tt] * msk[t] + qbv) * 0.25f;  // mask pre-proj, scale post-bias
            Kl[co_h][t][co_d] = ak[tt] + kbv;
            Vl[co_h][t][co_d] = av[tt] + vbv;
        }
    }
    __syncthreads();

    // ---- attention: wave h = head, lane = query token
    float q[16];
#pragma unroll
    for (int d4 = 0; d4 < 4; ++d4) {
        float4 qv = *reinterpret_cast<const float4*>(&Ql[h][lane][d4 * 4]);
        q[d4 * 4 + 0] = qv.x; q[d4 * 4 + 1] = qv.y;
        q[d4 * 4 + 2] = qv.z; q[d4 * 4 + 3] = qv.w;
    }
    const int i1 = lane >> 3, j1 = lane & 7;
    const float mn = msk[lane];
    float p[64];
#pragma unroll
    for (int m = 0; m < 64; ++m) {
        float s = 0.f;
#pragma unroll
        for (int d4 = 0; d4 < 4; ++d4) {
            float4 kv = *reinterpret_cast<const float4*>(&Kl[h][m][d4 * 4]);
            s += q[d4 * 4 + 0] * kv.x + q[d4 * 4 + 1] * kv.y
               + q[d4 * 4 + 2] * kv.z + q[d4 * 4 + 3] * kv.w;
        }
        int bidx = (i1 - (m >> 3) + 7) * 15 + (j1 - (m & 7) + 7);
        p[m] = s * mn * msk[m] + bl[bidx * 4 + h];
    }
    float mx = p[0];
#pragma unroll
    for (int m = 1; m < 64; ++m) mx = fmaxf(mx, p[m]);
    float sum = 0.f;
#pragma unroll
    for (int m = 0; m < 64; ++m) { p[m] = __expf(p[m] - mx); sum += p[m]; }
    float inv = 1.f / sum;
#pragma unroll
    for (int m = 0; m < 64; ++m) p[m] *= inv;

    // ---- head-mean attention (for next-finer level's atttransfer)
    if (attm) {
        for (int turn = 0; turn < 4; ++turn) {
            if (h == turn) {
                if (turn == 0) {
#pragma unroll
                    for (int m = 0; m < 64; ++m) AM[m][lane] = p[m] * 0.25f;
                } else {
#pragma unroll
                    for (int m = 0; m < 64; ++m) AM[m][lane] += p[m] * 0.25f;
                }
            }
            __syncthreads();
        }
        for (int r = tid; r < 4096; r += 256) {
            int t = r >> 6, m = r & 63;
            attm[(size_t)win * 4096 + r] = AM[m][t];
        }
    }

    // ---- PV
    float acc[16];
#pragma unroll
    for (int d = 0; d < 16; ++d) acc[d] = 0.f;
#pragma unroll
    for (int m = 0; m < 64; ++m) {
        float pm = p[m];
#pragma unroll
        for (int d4 = 0; d4 < 4; ++d4) {
            float4 vv = *reinterpret_cast<const float4*>(&Vl[h][m][d4 * 4]);
            acc[d4 * 4 + 0] += pm * vv.x; acc[d4 * 4 + 1] += pm * vv.y;
            acc[d4 * 4 + 2] += pm * vv.z; acc[d4 * 4 + 3] += pm * vv.w;
        }
    }
    // stage O into X (X free after projections): O[token][chan]
#pragma unroll
    for (int d = 0; d < 16; ++d) X[lane][h * 16 + d] = acc[d];
    __syncthreads();

    // ---- output projection: thread computes channel co=lane for 16 tokens of wave h
    {
        float o[16];
        float pbv = pb[lane];
#pragma unroll
        for (int tt = 0; tt < 16; ++tt) o[tt] = pbv;
        const float4* pw4 = reinterpret_cast<const float4*>(pw + lane * 64);
        for (int c4 = 0; c4 < 16; ++c4) {
            float4 w = pw4[c4];
#pragma unroll
            for (int tt = 0; tt < 16; ++tt) {
                int t = h * 16 + tt;
                float4 ov = *reinterpret_cast<const float4*>(&X[t][c4 * 4]);
                o[tt] += ov.x * w.x + ov.y * w.y + ov.z * w.z + ov.w * w.w;
            }
        }
#pragma unroll
        for (int tt = 0; tt < 16; ++tt) AM[lane][h * 16 + tt] = o[tt];
    }
    __syncthreads();
    // scatter to NCHW (8x32B segments per wave)
    for (int r = tid; r < 4096; r += 256) {
        int c = r >> 6, t = r & 63;
        aligned[(size_t)c * HW + (size_t)(y0 + (t >> 3)) * H + (x0 + (t & 7))] = AM[c][t];
    }
}

// ---------------------------------------------------------------------------
// atrans[c,Y,X] = sum_{mi,mj} attm[win, t(Y,X), mi*8+mj] * ta[c, wh*16+2mi+pi, ww*16+2mj+pj]
__global__ __launch_bounds__(256) void atttrans_kernel(const float* __restrict__ ta,
                                                       const float* __restrict__ attm,
                                                       float* __restrict__ out,
                                                       int H, int HW, int nWx16, int total) {
    int idx = blockIdx.x * 256 + threadIdx.x;
    if (idx >= total) return;
    int X = idx % H;
    int r1 = idx / H;
    int Y = r1 % H;
    int c = r1 / H;
    int wh = Y >> 4, ww = X >> 4;
    int win = wh * nWx16 + ww;
    int t = ((Y & 15) >> 1) * 8 + ((X & 15) >> 1);
    const float* ap = attm + ((size_t)win * 64 + t) * 64;
    const float* tp = ta + (size_t)c * HW
                         + (size_t)((wh << 4) + (Y & 1)) * H + (ww << 4) + (X & 1);
    float acc = 0.f;
#pragma unroll
    for (int mi = 0; mi < 8; ++mi) {
#pragma unroll
        for (int mj = 0; mj < 8; ++mj)
            acc = fmaf(ap[mi * 8 + mj], tp[(size_t)(mi * 2) * H + mj * 2], acc);
    }
    out[idx] = acc;
}

// ---------------------------------------------------------------------------
// Weight transform for tiled conv: Wt[((ci*3+ky)*3+kx)*64 + co] = fc_w[co][ci][ky][kx]
__global__ __launch_bounds__(256) void wtrans_kernel(const float* __restrict__ src,
                                                     float* __restrict__ dst) {
    int idx = blockIdx.x * 256 + threadIdx.x;   // 110592 total
    int co = idx & 63;
    int rest = idx >> 6;
    int kx = rest % 3;
    int r2 = rest / 3;
    int ky = r2 % 3;
    int ci = r2 / 3;
    dst[idx] = src[((co * 192 + ci) * 3 + ky) * 3 + kx];
}

// ---------------------------------------------------------------------------
// Tiled 3x3 SAME conv, 192->64 ch. Block = [64 co][4 y][32 x] output tile.
// 4 waves: wave wq owns co-slice [16*wq, 16*wq+16) -> weight reads are
// wave-uniform (scalar s_load path). Lane: y_l = lane>>5 owns rows {2y_l,2y_l+1},
// x = lane&31. Per-thread acc = 16co x 2y. Inputs double-buffered in LDS.
__global__ __launch_bounds__(256) void conv_tiled_kernel(
    const float* __restrict__ s0, const float* __restrict__ s1,
    const float* __restrict__ s2,
    const float* __restrict__ Wt,     // [(ci*3+ky)*3+kx][64co]
    const float* __restrict__ bias,
    float* __restrict__ out,
    int H, int HW, int apply_lrelu)
{
    __shared__ __align__(16) float Bl[2][8][6][40];  // x idx: 3=x0-1, 4..35=x0..x0+31, 36=x0+32

    const int tid = threadIdx.x;
    const int wq = __builtin_amdgcn_readfirstlane(tid >> 6);
    const int lane = tid & 63;
    const int y_l = lane >> 5;
    const int x = lane & 31;
    const int x0 = blockIdx.x * 32;
    const int y0 = blockIdx.y * 4;
    const int co0 = wq * 16;

    float acc[16][2];
#pragma unroll
    for (int cc = 0; cc < 16; ++cc) { acc[cc][0] = 0.f; acc[cc][1] = 0.f; }

    // staging: 384 aligned float4 slots + 96 halo scalars per chunk
    float4 stv[2];
    float sth = 0.f;

    auto stage_load = [&](int cb) {
#pragma unroll
        for (int s = 0; s < 2; ++s) {
            int slot = tid + s * 256;
            if (slot < 384) {
                int ci = cb + slot / 48;
                int rr = slot % 48;
                int row = rr >> 3, f4i = rr & 7;
                int y_src = y0 - 1 + row;
                const float* src = (ci < 64) ? s0 : ((ci < 128) ? s1 : s2);
                int cl = ci & 63;
                stv[s] = (y_src >= 0 && y_src < H)
                    ? *reinterpret_cast<const float4*>(
                          src + (size_t)cl * HW + (size_t)y_src * H + x0 + f4i * 4)
                    : make_float4(0.f, 0.f, 0.f, 0.f);
            }
        }
        if (tid < 96) {
            int ci = cb + tid / 12;
            int rr = tid % 12;
            int row = rr >> 1, side = rr & 1;
            int y_src = y0 - 1 + row;
            int xg = side ? (x0 + 32) : (x0 - 1);
            const float* src = (ci < 64) ? s0 : ((ci < 128) ? s1 : s2);
            int cl = ci & 63;
            sth = (y_src >= 0 && y_src < H && xg >= 0 && xg < H)
                ? src[(size_t)cl * HW + (size_t)y_src * H + xg] : 0.f;
        }
    };
    auto stage_write = [&](int buf) {
#pragma unroll
        for (int s = 0; s < 2; ++s) {
            int slot = tid + s * 256;
            if (slot < 384) {
                int ci_l = slot / 48;
                int rr = slot % 48;
                int row = rr >> 3, f4i = rr & 7;
                *reinterpret_cast<float4*>(&Bl[buf][ci_l][row][4 + f4i * 4]) = stv[s];
            }
        }
        if (tid < 96) {
            int ci_l = tid / 12;
            int rr = tid % 12;
            Bl[buf][ci_l][rr >> 1][(rr & 1) ? 36 : 3] = sth;
        }
    };

    stage_load(0);
    stage_write(0);
    __syncthreads();

    for (int c = 0; c < 24; ++c) {
        int buf = c & 1;
        if (c < 23) stage_load((c + 1) * 8);   // issue next chunk's VMEM early
        int cb = c * 8;
        for (int ci_l = 0; ci_l < 8; ++ci_l) {
#pragma unroll
            for (int ky = 0; ky < 3; ++ky) {
                int k3 = ((cb + ci_l) * 3 + ky) * 3;
                float w[3][16];   // wave-uniform -> SGPRs
#pragma unroll
                for (int kx = 0; kx < 3; ++kx) {
                    const float4* wp = reinterpret_cast<const float4*>(
                        Wt + (size_t)(k3 + kx) * 64 + co0);
#pragma unroll
                    for (int qq = 0; qq < 4; ++qq) {
                        float4 v = wp[qq];
                        w[kx][qq * 4 + 0] = v.x; w[kx][qq * 4 + 1] = v.y;
                        w[kx][qq * 4 + 2] = v.z; w[kx][qq * 4 + 3] = v.w;
                    }
                }
#pragma unroll
                for (int yy = 0; yy < 2; ++yy) {
                    const float* br = &Bl[buf][ci_l][y_l * 2 + yy + ky][x + 3];
                    float i0 = br[0], i1 = br[1], i2 = br[2];
#pragma unroll
                    for (int cc = 0; cc < 16; ++cc)
                        acc[cc][yy] = fmaf(w[0][cc], i0,
                                       fmaf(w[1][cc], i1,
                                        fmaf(w[2][cc], i2, acc[cc][yy])));
                }
            }
        }
        if (c < 23) {
            __syncthreads();
            stage_write(buf ^ 1);
            __syncthreads();
        }
    }

    // epilogue: bias (+ optional lrelu), row-coalesced stores
    const int yb = y0 + y_l * 2;
#pragma unroll
    for (int cc = 0; cc < 16; ++cc) {
        float bv = bias[co0 + cc];
#pragma unroll
        for (int yy = 0; yy < 2; ++yy) {
            float v = acc[cc][yy] + bv;
            if (apply_lrelu) v = LRELU(v);
            out[(size_t)(co0 + cc) * HW + (size_t)(yb + yy) * H + x0 + x] = v;
        }
    }
}

// ---------------------------------------------------------------------------
// 2x bilinear upsample of lrelu(in); jax.image.resize linear semantics.
__global__ __launch_bounds__(256) void upsample_kernel(const float* __restrict__ in,
                                                       float* __restrict__ out,
                                                       int Hin, int total) {
    int idx = blockIdx.x * 256 + threadIdx.x;
    if (idx >= total) return;
    int W2 = Hin * 2;
    int X = idx % W2;
    int r1 = idx / W2;
    int Y = r1 % W2;
    int c = r1 / W2;
    int y0 = Y >> 1, x0 = X >> 1;
    int ya = (Y & 1) ? y0 + 1 : y0 - 1;
    int xa = (X & 1) ? x0 + 1 : x0 - 1;
    ya = ya < 0 ? 0 : (ya >= Hin ? Hin - 1 : ya);
    xa = xa < 0 ? 0 : (xa >= Hin ? Hin - 1 : xa);
    const float* pbase = in + (size_t)c * Hin * Hin;
    float v00 = LRELU(pbase[(size_t)y0 * Hin + x0]);
    float v01 = LRELU(pbase[(size_t)y0 * Hin + xa]);
    float v10 = LRELU(pbase[(size_t)ya * Hin + x0]);
    float v11 = LRELU(pbase[(size_t)ya * Hin + xa]);
    out[idx] = 0.5625f * v00 + 0.1875f * (v01 + v10) + 0.0625f * v11;
}

// ---------------------------------------------------------------------------
extern "C" void kernel_launch(void* const* d_in, const int* in_sizes, int n_in,
                              void* d_out, int out_size, void* d_ws, size_t ws_size,
                              hipStream_t stream) {
    const float* refs[3] = { (const float*)d_in[0], (const float*)d_in[1], (const float*)d_in[2] };
    const float* tas[3]  = { (const float*)d_in[3], (const float*)d_in[4], (const float*)d_in[5] };
    const float* q_w = (const float*)d_in[6];
    const float* q_b = (const float*)d_in[7];
    const float* k_w = (const float*)d_in[8];
    const float* k_b = (const float*)d_in[9];
    const float* v_w = (const float*)d_in[10];
    const float* v_b = (const float*)d_in[11];
    const float* p_w = (const float*)d_in[12];
    const float* p_b = (const float*)d_in[13];
    const float* btab = (const float*)d_in[14];
    const float* fc_w = (const float*)d_in[15];
    const float* fc_b = (const float*)d_in[16];

    // per-batch scratch (reused across batches): ~61 MB total
    float* ws = (float*)d_ws;
    float* ALIGNED = ws;                  // 4,194,304 floats (64 x 256 x 256)
    float* ATRANS  = ws + 4194304;        // 4,194,304
    float* UPS     = ws + 8388608;        // 4,194,304
    float* FEAT2   = ws + 12582912;       // 1,048,576 (64 x 128 x 128)
    float* ATTMA   = ws + 13631488;       //   262,144 (64 win x 64 x 64)
    float* ATTMB   = ws + 13893632;       // 1,048,576 (256 win x 64 x 64)
    float* WT0     = ws + 14942208;       //   110,592 (transformed fc_w[0])
    float* WT1     = ws + 15052800;       //   110,592 (transformed fc_w[1])

    // one-time weight transforms (before batch loop)
    wtrans_kernel<<<432, 256, 0, stream>>>(fc_w, WT0);
    wtrans_kernel<<<432, 256, 0, stream>>>(fc_w + 110592, WT1);

    const int Hs[3] = { 256, 128, 64 };
    for (int b = 0; b < 4; ++b) {
        for (int j = 2; j >= 0; --j) {
            int H = Hs[j];
            int HW = H * H;
            int nWx = H / 8;
            int nWin = nWx * nWx;
            const float* ref_b = refs[j] + (size_t)b * 64 * HW;
            const float* ta_b  = tas[j]  + (size_t)b * 64 * HW;
            float* attm_out = (j == 2) ? ATTMA : ((j == 1) ? ATTMB : nullptr);

            fused_attn_kernel<<<nWin, 256, 0, stream>>>(
                ref_b, ta_b,
                q_w + j * 4096, q_b + j * 64, k_w + j * 4096, k_b + j * 64,
                v_w + j * 4096, v_b + j * 64, p_w + j * 4096, p_b + j * 64,
                btab + j * 900, ALIGNED, attm_out, H, nWx);

            if (j < 2) {
                const float* attm_in = (j == 1) ? ATTMA : ATTMB;  // coarser level's attn
                atttrans_kernel<<<(64 * HW) / 256, 256, 0, stream>>>(
                    ta_b, attm_in, ATRANS, H, HW, H / 16, 64 * HW);
                conv_tiled_kernel<<<dim3(H / 32, H / 4), 256, 0, stream>>>(
                    ALIGNED, UPS, ATRANS, (j == 0) ? WT0 : WT1, fc_b + j * 64,
                    j == 0 ? ((float*)d_out + (size_t)b * 64 * HW) : FEAT2,
                    H, HW, j == 0 ? 1 : 0);
            }
            if (j > 0) {
                const float* upin = (j == 2) ? ALIGNED : FEAT2;   // lrelu applied in-kernel
                upsample_kernel<<<(64 * 4 * HW) / 256, 256, 0, stream>>>(
                    upin, UPS, H, 64 * 4 * HW);
            }
        }
    }
}

// Round 5
// 2495.077 us; speedup vs baseline: 7.6581x; 1.7253x over previous
//
#include <hip/hip_runtime.h>
#include <hip/hip_bf16.h>
#include <math.h>

#define LRELU(v) ((v) >= 0.f ? (v) : 0.1f * (v))

__device__ __forceinline__ float b2f(unsigned short u) {
    union { unsigned int i; float f; } x; x.i = ((unsigned int)u) << 16; return x.f;
}
__device__ __forceinline__ float loadf(const float* p) { return *p; }
__device__ __forceinline__ float loadf(const __hip_bfloat16* p) { return __bfloat162float(*p); }

// ---------------------------------------------------------------------------
// Fused per-window cross attention. Block = one 8x8 window of one batch image.
// grid.x = nWin, grid.y = NB. 4 waves = 4 heads. LDS = 79.6 KB -> 2 blocks/CU.
__global__ __launch_bounds__(256) void fused_attn_kernel(
    const float* __restrict__ ref,   // [NB][64][H][H]
    const float* __restrict__ ta,
    const float* __restrict__ qw, const float* __restrict__ qb,
    const float* __restrict__ kw, const float* __restrict__ kb,
    const float* __restrict__ vw, const float* __restrict__ vb,
    const float* __restrict__ pw, const float* __restrict__ pb,
    const float* __restrict__ btab,  // [225][4]
    __hip_bfloat16* __restrict__ aligned,  // [NB][64][H][H]
    float* __restrict__ attm,        // [NB][nWin][64][64] head-mean attn, or null
    int H, int nWx, int nWin)
{
    __shared__ __align__(16) float SM[19908];
    float (*X)[68] = reinterpret_cast<float(*)[68]>(SM);                  // ref win; later O staging
    float (*Y)[68] = reinterpret_cast<float(*)[68]>(SM + 4352);           // ta win; later AM staging
    float (*Kl)[64][20] = reinterpret_cast<float(*)[64][20]>(SM + 8704);
    float (*Vl)[64][20] = reinterpret_cast<float(*)[64][20]>(SM + 13824);
    float* bl  = SM + 18944;   // 900
    float* msk = SM + 19844;   // 64
    float (*AMa)[65] = reinterpret_cast<float(*)[65]>(SM + 4352);         // alias Y
    float (*AMo)[65] = reinterpret_cast<float(*)[65]>(SM + 4352);         // alias Y

    const int HW = H * H;
    const int win = blockIdx.x;
    const int bb = blockIdx.y;
    const int wy = win / nWx, wx = win - wy * nWx;
    const int y0 = wy * 8, x0 = wx * 8;
    const int tid = threadIdx.x;
    const size_t bbase = (size_t)bb * 64 * HW;

    for (int r = tid; r < 4096; r += 256) {
        int c = r >> 6, t = r & 63;
        size_t off = bbase + (size_t)c * HW + (size_t)(y0 + (t >> 3)) * H + (x0 + (t & 7));
        X[t][c] = ref[off];
        Y[t][c] = ta[off];
    }
    for (int r = tid; r < 900; r += 256) bl[r] = btab[r];
    __syncthreads();

    if (tid < 64) {
        float s = 0.f;
#pragma unroll
        for (int c = 0; c < 64; ++c) s += (X[tid][c] > 0.95f) ? 0.f : 1.f;
        msk[tid] = s * (1.f / 64.f);
    }
    __syncthreads();

    const int h = __builtin_amdgcn_readfirstlane(tid >> 6);
    const int lane = tid & 63;

    // ---- per-thread Q: thread (wave h, lane) computes q[d] for (head h, query token lane)
    float q[16];
#pragma unroll
    for (int d = 0; d < 16; ++d) q[d] = 0.f;
    {
        const float* qwh = qw + h * 16 * 64;   // wave-uniform -> scalar loads
#pragma unroll
        for (int c4 = 0; c4 < 16; ++c4) {
            float4 xv = *reinterpret_cast<const float4*>(&X[lane][c4 * 4]);
#pragma unroll
            for (int d = 0; d < 16; ++d) {
                const float4 wv = *reinterpret_cast<const float4*>(qwh + d * 64 + c4 * 4);
                q[d] += xv.x * wv.x + xv.y * wv.y + xv.z * wv.z + xv.w * wv.w;
            }
        }
        float mn0 = msk[lane];
#pragma unroll
        for (int d = 0; d < 16; ++d) q[d] = (q[d] * mn0 + qb[h * 16 + d]) * 0.25f;
    }

    // ---- coop K/V: thread computes channel co=lane for tokens t = h*16+tt (Y reads broadcast)
    {
        float ak[16], av[16];
#pragma unroll
        for (int tt = 0; tt < 16; ++tt) { ak[tt] = 0.f; av[tt] = 0.f; }
        const float4* kw4 = reinterpret_cast<const float4*>(kw + lane * 64);
        const float4* vw4 = reinterpret_cast<const float4*>(vw + lane * 64);
        for (int c4 = 0; c4 < 16; ++c4) {
            float4 wk = kw4[c4], wv = vw4[c4];
#pragma unroll
            for (int tt = 0; tt < 16; ++tt) {
                int t = h * 16 + tt;
                float4 yv = *reinterpret_cast<const float4*>(&Y[t][c4 * 4]);
                ak[tt] += yv.x * wk.x + yv.y * wk.y + yv.z * wk.z + yv.w * wk.w;
                av[tt] += yv.x * wv.x + yv.y * wv.y + yv.z * wv.z + yv.w * wv.w;
            }
        }
        float kbv = kb[lane], vbv = vb[lane];
        int co_h = lane >> 4, co_d = lane & 15;
#pragma unroll
        for (int tt = 0; tt < 16; ++tt) {
            int t = h * 16 + tt;
            Kl[co_h][t][co_d] = ak[tt] + kbv;
            Vl[co_h][t][co_d] = av[tt] + vbv;
        }
    }
    __syncthreads();

    // ---- attention scores (Kl reads are wave-broadcast, conflict-free)
    const int i1 = lane >> 3, j1 = lane & 7;
    const float mn = msk[lane];
    float p[64];
#pragma unroll
    for (int m = 0; m < 64; ++m) {
        float s = 0.f;
#pragma unroll
        for (int d4 = 0; d4 < 4; ++d4) {
            float4 kv = *reinterpret_cast<const float4*>(&Kl[h][m][d4 * 4]);
            s += q[d4 * 4 + 0] * kv.x + q[d4 * 4 + 1] * kv.y
               + q[d4 * 4 + 2] * kv.z + q[d4 * 4 + 3] * kv.w;
        }
        int bidx = (i1 - (m >> 3) + 7) * 15 + (j1 - (m & 7) + 7);
        p[m] = s * mn * msk[m] + bl[bidx * 4 + h];
    }
    float mx = p[0];
#pragma unroll
    for (int m = 1; m < 64; ++m) mx = fmaxf(mx, p[m]);
    float sum = 0.f;
#pragma unroll
    for (int m = 0; m < 64; ++m) { p[m] = __expf(p[m] - mx); sum += p[m]; }
    float inv = 1.f / sum;
#pragma unroll
    for (int m = 0; m < 64; ++m) p[m] *= inv;

    // ---- head-mean attention (into Y region; Y dead after proj)
    if (attm) {
        for (int turn = 0; turn < 4; ++turn) {
            if (h == turn) {
                if (turn == 0) {
#pragma unroll
                    for (int m = 0; m < 64; ++m) AMa[m][lane] = p[m] * 0.25f;
                } else {
#pragma unroll
                    for (int m = 0; m < 64; ++m) AMa[m][lane] += p[m] * 0.25f;
                }
            }
            __syncthreads();
        }
        float* ap = attm + ((size_t)bb * nWin + win) * 4096;
        for (int r = tid; r < 4096; r += 256) ap[r] = AMa[r >> 6][r & 63];
        __syncthreads();   // AMa reads done before AMo overwrites Y region
    }

    // ---- PV
    float acc[16];
#pragma unroll
    for (int d = 0; d < 16; ++d) acc[d] = 0.f;
#pragma unroll
    for (int m = 0; m < 64; ++m) {
        float pm = p[m];
#pragma unroll
        for (int d4 = 0; d4 < 4; ++d4) {
            float4 vv = *reinterpret_cast<const float4*>(&Vl[h][m][d4 * 4]);
            acc[d4 * 4 + 0] += pm * vv.x; acc[d4 * 4 + 1] += pm * vv.y;
            acc[d4 * 4 + 2] += pm * vv.z; acc[d4 * 4 + 3] += pm * vv.w;
        }
    }
    // stage O into X region (X dead after Q-proj): O[token][chan]
#pragma unroll
    for (int d = 0; d < 16; ++d) X[lane][h * 16 + d] = acc[d];
    __syncthreads();

    // ---- output projection: channel co=lane for tokens t=h*16+tt; stage into Y region
    {
        float o[16];
        float pbv = pb[lane];
#pragma unroll
        for (int tt = 0; tt < 16; ++tt) o[tt] = pbv;
        const float4* pw4 = reinterpret_cast<const float4*>(pw + lane * 64);
        for (int c4 = 0; c4 < 16; ++c4) {
            float4 w = pw4[c4];
#pragma unroll
            for (int tt = 0; tt < 16; ++tt) {
                int t = h * 16 + tt;
                float4 ov = *reinterpret_cast<const float4*>(&X[t][c4 * 4]);
                o[tt] += ov.x * w.x + ov.y * w.y + ov.z * w.z + ov.w * w.w;
            }
        }
#pragma unroll
        for (int tt = 0; tt < 16; ++tt) AMo[lane][h * 16 + tt] = o[tt];
    }
    __syncthreads();
    // scatter to NCHW bf16 (8 px = 16 B segments)
    for (int r = tid; r < 4096; r += 256) {
        int c = r >> 6, t = r & 63;
        aligned[bbase + (size_t)c * HW + (size_t)(y0 + (t >> 3)) * H + (x0 + (t & 7))]
            = __float2bfloat16(AMo[c][t]);
    }
}

// ---------------------------------------------------------------------------
// atrans[b,c,Y,X] = sum_{mi,mj} attm[b,win,t(Y,X),mi*8+mj] * ta[b,c,...]
__global__ __launch_bounds__(256) void atttrans_kernel(const float* __restrict__ ta,
                                                       const float* __restrict__ attm,
                                                       __hip_bfloat16* __restrict__ out,
                                                       int H, int HW, int nWx16, int nWinAtt,
                                                       int total) {
    int idx = blockIdx.x * 256 + threadIdx.x;
    if (idx >= total) return;
    int X = idx % H;
    int r1 = idx / H;
    int Y = r1 % H;
    int r2 = r1 / H;
    int c = r2 & 63;
    int b = r2 >> 6;
    int wh = Y >> 4, ww = X >> 4;
    int win = wh * nWx16 + ww;
    int t = ((Y & 15) >> 1) * 8 + ((X & 15) >> 1);
    const float* ap = attm + (((size_t)b * nWinAtt + win) * 64 + t) * 64;
    const float* tp = ta + ((size_t)b * 64 + c) * HW
                         + (size_t)((wh << 4) + (Y & 1)) * H + (ww << 4) + (X & 1);
    float acc = 0.f;
#pragma unroll
    for (int mi = 0; mi < 8; ++mi) {
#pragma unroll
        for (int mj = 0; mj < 8; ++mj)
            acc = fmaf(ap[mi * 8 + mj], tp[(size_t)(mi * 2) * H + mj * 2], acc);
    }
    out[idx] = __float2bfloat16(acc);
}

// ---------------------------------------------------------------------------
// Weight transform: Wt[((ci*3+ky)*3+kx)*64 + co] = fc_w[co][ci][ky][kx]
__global__ __launch_bounds__(256) void wtrans_kernel(const float* __restrict__ src,
                                                     float* __restrict__ dst) {
    int idx = blockIdx.x * 256 + threadIdx.x;   // 110592 total
    int co = idx & 63;
    int rest = idx >> 6;
    int kx = rest % 3;
    int r2 = rest / 3;
    int ky = r2 % 3;
    int ci = r2 / 3;
    dst[idx] = src[((co * 192 + ci) * 3 + ky) * 3 + kx];
}

// ---------------------------------------------------------------------------
// Tiled 3x3 SAME conv, 192->64 ch, bf16 inputs, f32 out. Block = [64co][4y][32x].
// grid.z = batch. Wave wq owns co-slice (scalar weight loads); lane = (y pair, x).
__global__ __launch_bounds__(256) void conv_tiled_kernel(
    const __hip_bfloat16* __restrict__ s0, const __hip_bfloat16* __restrict__ s1,
    const __hip_bfloat16* __restrict__ s2,
    const float* __restrict__ Wt,
    const float* __restrict__ bias,
    float* __restrict__ out,
    int H, int HW, int apply_lrelu)
{
    __shared__ __align__(16) float Bl[2][8][6][40];

    const int tid = threadIdx.x;
    const int wq = __builtin_amdgcn_readfirstlane(tid >> 6);
    const int lane = tid & 63;
    const int y_l = lane >> 5;
    const int x = lane & 31;
    const int x0 = blockIdx.x * 32;
    const int y0 = blockIdx.y * 4;
    const int co0 = wq * 16;
    const size_t zoff = (size_t)blockIdx.z * 64 * HW;
    const unsigned short* b0 = (const unsigned short*)s0 + zoff;
    const unsigned short* b1 = (const unsigned short*)s1 + zoff;
    const unsigned short* b2 = (const unsigned short*)s2 + zoff;

    float acc[16][2];
#pragma unroll
    for (int cc = 0; cc < 16; ++cc) { acc[cc][0] = 0.f; acc[cc][1] = 0.f; }

    ushort4 stv[2];
    unsigned short sth = 0;

    auto stage_load = [&](int cb) {
#pragma unroll
        for (int s = 0; s < 2; ++s) {
            int slot = tid + s * 256;
            if (slot < 384) {
                int ci = cb + slot / 48;
                int rr = slot % 48;
                int row = rr >> 3, f4i = rr & 7;
                int y_src = y0 - 1 + row;
                const unsigned short* src = (ci < 64) ? b0 : ((ci < 128) ? b1 : b2);
                int cl = ci & 63;
                stv[s] = (y_src >= 0 && y_src < H)
                    ? *reinterpret_cast<const ushort4*>(
                          src + (size_t)cl * HW + (size_t)y_src * H + x0 + f4i * 4)
                    : make_ushort4(0, 0, 0, 0);
            }
        }
        if (tid < 96) {
            int ci = cb + tid / 12;
            int rr = tid % 12;
            int row = rr >> 1, side = rr & 1;
            int y_src = y0 - 1 + row;
            int xg = side ? (x0 + 32) : (x0 - 1);
            const unsigned short* src = (ci < 64) ? b0 : ((ci < 128) ? b1 : b2);
            int cl = ci & 63;
            sth = (y_src >= 0 && y_src < H && xg >= 0 && xg < H)
                ? src[(size_t)cl * HW + (size_t)y_src * H + xg] : (unsigned short)0;
        }
    };
    auto stage_write = [&](int buf) {
#pragma unroll
        for (int s = 0; s < 2; ++s) {
            int slot = tid + s * 256;
            if (slot < 384) {
                int ci_l = slot / 48;
                int rr = slot % 48;
                int row = rr >> 3, f4i = rr & 7;
                float4 f = make_float4(b2f(stv[s].x), b2f(stv[s].y),
                                       b2f(stv[s].z), b2f(stv[s].w));
                *reinterpret_cast<float4*>(&Bl[buf][ci_l][row][4 + f4i * 4]) = f;
            }
        }
        if (tid < 96) {
            int ci_l = tid / 12;
            int rr = tid % 12;
            Bl[buf][ci_l][rr >> 1][(rr & 1) ? 36 : 3] = b2f(sth);
        }
    };

    stage_load(0);
    stage_write(0);
    __syncthreads();

    for (int c = 0; c < 24; ++c) {
        int buf = c & 1;
        if (c < 23) stage_load((c + 1) * 8);
        int cb = c * 8;
        for (int ci_l = 0; ci_l < 8; ++ci_l) {
#pragma unroll
            for (int ky = 0; ky < 3; ++ky) {
                int k3 = ((cb + ci_l) * 3 + ky) * 3;
                float w[3][16];   // wave-uniform -> SGPRs
#pragma unroll
                for (int kx = 0; kx < 3; ++kx) {
                    const float4* wp = reinterpret_cast<const float4*>(
                        Wt + (size_t)(k3 + kx) * 64 + co0);
#pragma unroll
                    for (int qq = 0; qq < 4; ++qq) {
                        float4 v = wp[qq];
                        w[kx][qq * 4 + 0] = v.x; w[kx][qq * 4 + 1] = v.y;
                        w[kx][qq * 4 + 2] = v.z; w[kx][qq * 4 + 3] = v.w;
                    }
                }
#pragma unroll
                for (int yy = 0; yy < 2; ++yy) {
                    const float* br = &Bl[buf][ci_l][y_l * 2 + yy + ky][x + 3];
                    float i0 = br[0], i1 = br[1], i2 = br[2];
#pragma unroll
                    for (int cc = 0; cc < 16; ++cc)
                        acc[cc][yy] = fmaf(w[0][cc], i0,
                                       fmaf(w[1][cc], i1,
                                        fmaf(w[2][cc], i2, acc[cc][yy])));
                }
            }
        }
        if (c < 23) {
            __syncthreads();
            stage_write(buf ^ 1);
            __syncthreads();
        }
    }

    const int yb = y0 + y_l * 2;
    float* outz = out + zoff;
#pragma unroll
    for (int cc = 0; cc < 16; ++cc) {
        float bv = bias[co0 + cc];
#pragma unroll
        for (int yy = 0; yy < 2; ++yy) {
            float v = acc[cc][yy] + bv;
            if (apply_lrelu) v = LRELU(v);
            outz[(size_t)(co0 + cc) * HW + (size_t)(yb + yy) * H + x0 + x] = v;
        }
    }
}

// ---------------------------------------------------------------------------
// 2x bilinear upsample of lrelu(in); jax.image.resize linear semantics. Batched.
template <typename T>
__global__ __launch_bounds__(256) void upsample_kernel(const T* __restrict__ in,
                                                       __hip_bfloat16* __restrict__ out,
                                                       int Hin, int total) {
    int idx = blockIdx.x * 256 + threadIdx.x;
    if (idx >= total) return;
    int W2 = Hin * 2;
    int X = idx % W2;
    int r1 = idx / W2;
    int Y = r1 % W2;
    int bc = r1 / W2;
    int y0 = Y >> 1, x0 = X >> 1;
    int ya = (Y & 1) ? y0 + 1 : y0 - 1;
    int xa = (X & 1) ? x0 + 1 : x0 - 1;
    ya = ya < 0 ? 0 : (ya >= Hin ? Hin - 1 : ya);
    xa = xa < 0 ? 0 : (xa >= Hin ? Hin - 1 : xa);
    const T* pbase = in + (size_t)bc * Hin * Hin;
    float v00 = LRELU(loadf(pbase + (size_t)y0 * Hin + x0));
    float v01 = LRELU(loadf(pbase + (size_t)y0 * Hin + xa));
    float v10 = LRELU(loadf(pbase + (size_t)ya * Hin + x0));
    float v11 = LRELU(loadf(pbase + (size_t)ya * Hin + xa));
    out[idx] = __float2bfloat16(0.5625f * v00 + 0.1875f * (v01 + v10) + 0.0625f * v11);
}

// ---------------------------------------------------------------------------
extern "C" void kernel_launch(void* const* d_in, const int* in_sizes, int n_in,
                              void* d_out, int out_size, void* d_ws, size_t ws_size,
                              hipStream_t stream) {
    const float* refs[3] = { (const float*)d_in[0], (const float*)d_in[1], (const float*)d_in[2] };
    const float* tas[3]  = { (const float*)d_in[3], (const float*)d_in[4], (const float*)d_in[5] };
    const float* q_w = (const float*)d_in[6];
    const float* q_b = (const float*)d_in[7];
    const float* k_w = (const float*)d_in[8];
    const float* k_b = (const float*)d_in[9];
    const float* v_w = (const float*)d_in[10];
    const float* v_b = (const float*)d_in[11];
    const float* p_w = (const float*)d_in[12];
    const float* p_b = (const float*)d_in[13];
    const float* btab = (const float*)d_in[14];
    const float* fc_w = (const float*)d_in[15];
    const float* fc_b = (const float*)d_in[16];

    // Workspace layout. Full-batch (NB=4) needs ~102 MB of d_ws (+ scratch in
    // d_out); fall back to per-batch (NB=1, ~36 MB) if ws_size is small.
    const size_t FULL_NEED = 2ull * 442368 + 3ull * 16777216 * 2 + 1024;
    const int NB = (ws_size >= FULL_NEED) ? 4 : 1;

    char* p = (char*)d_ws;
    float* WT0 = (float*)p;  p += 442368;
    float* WT1 = (float*)p;  p += 442368;
    __hip_bfloat16* ALIGNED = (__hip_bfloat16*)p;  p += (size_t)NB * 64 * 65536 * 2;
    __hip_bfloat16* ATRANS  = (__hip_bfloat16*)p;  p += (size_t)NB * 64 * 65536 * 2;
    __hip_bfloat16* UPS     = (__hip_bfloat16*)p;  p += (size_t)NB * 64 * 65536 * 2;
    float *ATTMA, *ATTMB, *FEAT2;
    if (NB == 4) {
        // d_out as scratch: all three regions dead before the final conv writes d_out
        ATTMA = (float*)d_out;                     // 4*64*4096   = 1,048,576 f
        ATTMB = (float*)d_out + 1048576;           // 4*256*4096  = 4,194,304 f
        FEAT2 = (float*)d_out + 5242880;           // 4*64*16384  = 4,194,304 f
    } else {
        ATTMA = (float*)p;  p += (size_t)NB * 64 * 4096 * 4;
        ATTMB = (float*)p;  p += (size_t)NB * 256 * 4096 * 4;
        FEAT2 = (float*)p;  p += (size_t)NB * 64 * 16384 * 4;
    }

    wtrans_kernel<<<432, 256, 0, stream>>>(fc_w, WT0);
    wtrans_kernel<<<432, 256, 0, stream>>>(fc_w + 110592, WT1);

    for (int b0 = 0; b0 < 4; b0 += NB) {
        const float* ref1 = refs[0] + (size_t)b0 * 64 * 65536;
        const float* ta1  = tas[0]  + (size_t)b0 * 64 * 65536;
        const float* ref2 = refs[1] + (size_t)b0 * 64 * 16384;
        const float* ta2  = tas[1]  + (size_t)b0 * 64 * 16384;
        const float* ref3 = refs[2] + (size_t)b0 * 64 * 4096;
        const float* ta3  = tas[2]  + (size_t)b0 * 64 * 4096;

        // ---- level j=2 (H=64, nWin=64)
        fused_attn_kernel<<<dim3(64, NB), 256, 0, stream>>>(
            ref3, ta3, q_w + 2*4096, q_b + 2*64, k_w + 2*4096, k_b + 2*64,
            v_w + 2*4096, v_b + 2*64, p_w + 2*4096, p_b + 2*64,
            btab + 2*900, ALIGNED, ATTMA, 64, 8, 64);
        upsample_kernel<__hip_bfloat16><<<(NB * 64 * 16384) / 256, 256, 0, stream>>>(
            ALIGNED, UPS, 64, NB * 64 * 16384);

        // ---- level j=1 (H=128, nWin=256)
        fused_attn_kernel<<<dim3(256, NB), 256, 0, stream>>>(
            ref2, ta2, q_w + 4096, q_b + 64, k_w + 4096, k_b + 64,
            v_w + 4096, v_b + 64, p_w + 4096, p_b + 64,
            btab + 900, ALIGNED, ATTMB, 128, 16, 256);
        atttrans_kernel<<<(NB * 64 * 16384) / 256, 256, 0, stream>>>(
            ta2, ATTMA, ATRANS, 128, 16384, 8, 64, NB * 64 * 16384);
        conv_tiled_kernel<<<dim3(4, 32, NB), 256, 0, stream>>>(
            ALIGNED, UPS, ATRANS, WT1, fc_b + 64, FEAT2, 128, 16384, 0);
        upsample_kernel<float><<<(NB * 64 * 65536) / 256, 256, 0, stream>>>(
            FEAT2, UPS, 128, NB * 64 * 65536);

        // ---- level j=0 (H=256, nWin=1024)
        fused_attn_kernel<<<dim3(1024, NB), 256, 0, stream>>>(
            ref1, ta1, q_w, q_b, k_w, k_b, v_w, v_b, p_w, p_b,
            btab, ALIGNED, nullptr, 256, 32, 1024);
        atttrans_kernel<<<(NB * 64 * 65536) / 256, 256, 0, stream>>>(
            ta1, ATTMB, ATRANS, 256, 65536, 16, 256, NB * 64 * 65536);
        conv_tiled_kernel<<<dim3(8, 64, NB), 256, 0, stream>>>(
            ALIGNED, UPS, ATRANS, WT0, fc_b,
            (float*)d_out + (size_t)b0 * 64 * 65536, 256, 65536, 1);
    }
}

// Round 6
// 1284.754 us; speedup vs baseline: 14.8725x; 1.9421x over previous
//
#include <hip/hip_runtime.h>
#include <hip/hip_bf16.h>
#include <math.h>

#define LRELU(v) ((v) >= 0.f ? (v) : 0.1f * (v))

typedef __attribute__((ext_vector_type(8))) short short8;
typedef __attribute__((ext_vector_type(4))) float f32x4;

__device__ __forceinline__ float loadf(const float* p) { return *p; }
__device__ __forceinline__ float loadf(const __hip_bfloat16* p) { return __bfloat162float(*p); }
__device__ __forceinline__ short f2bfbits(float f) {
    __hip_bfloat16 h = __float2bfloat16(f);
    return *reinterpret_cast<short*>(&h);
}

// ---------------------------------------------------------------------------
// Fused per-window cross attention. Block = one 8x8 window of one batch image.
// grid.x = nWin, grid.y = NB. 4 waves = 4 heads. Output: NHWC bf16.
__global__ __launch_bounds__(256) void fused_attn_kernel(
    const float* __restrict__ ref,   // [NB][64][H][H] NCHW f32
    const float* __restrict__ ta,
    const float* __restrict__ qw, const float* __restrict__ qb,
    const float* __restrict__ kw, const float* __restrict__ kb,
    const float* __restrict__ vw, const float* __restrict__ vb,
    const float* __restrict__ pw, const float* __restrict__ pb,
    const float* __restrict__ btab,  // [225][4]
    __hip_bfloat16* __restrict__ aligned,  // [NB][H][H][64] NHWC bf16
    float* __restrict__ attm,        // [NB][nWin][64][64] head-mean attn, or null
    int H, int nWx, int nWin)
{
    __shared__ __align__(16) float SM[19908];
    float (*X)[68] = reinterpret_cast<float(*)[68]>(SM);                  // ref win; later O staging
    float (*Y)[68] = reinterpret_cast<float(*)[68]>(SM + 4352);           // ta win; later AM staging
    float (*Kl)[64][20] = reinterpret_cast<float(*)[64][20]>(SM + 8704);
    float (*Vl)[64][20] = reinterpret_cast<float(*)[64][20]>(SM + 13824);
    float* bl  = SM + 18944;   // 900
    float* msk = SM + 19844;   // 64
    float (*AMa)[65] = reinterpret_cast<float(*)[65]>(SM + 4352);         // alias Y
    float (*AMo)[65] = reinterpret_cast<float(*)[65]>(SM + 4352);         // alias Y

    const int HW = H * H;
    const int win = blockIdx.x;
    const int bb = blockIdx.y;
    const int wy = win / nWx, wx = win - wy * nWx;
    const int y0 = wy * 8, x0 = wx * 8;
    const int tid = threadIdx.x;
    const size_t bbase = (size_t)bb * 64 * HW;

    for (int r = tid; r < 4096; r += 256) {
        int c = r >> 6, t = r & 63;
        size_t off = bbase + (size_t)c * HW + (size_t)(y0 + (t >> 3)) * H + (x0 + (t & 7));
        X[t][c] = ref[off];
        Y[t][c] = ta[off];
    }
    for (int r = tid; r < 900; r += 256) bl[r] = btab[r];
    __syncthreads();

    if (tid < 64) {
        float s = 0.f;
#pragma unroll
        for (int c = 0; c < 64; ++c) s += (X[tid][c] > 0.95f) ? 0.f : 1.f;
        msk[tid] = s * (1.f / 64.f);
    }
    __syncthreads();

    const int h = __builtin_amdgcn_readfirstlane(tid >> 6);
    const int lane = tid & 63;

    // ---- per-thread Q: thread (wave h, lane) computes q[d] for (head h, query token lane)
    float q[16];
#pragma unroll
    for (int d = 0; d < 16; ++d) q[d] = 0.f;
    {
        const float* qwh = qw + h * 16 * 64;   // wave-uniform -> scalar loads
#pragma unroll
        for (int c4 = 0; c4 < 16; ++c4) {
            float4 xv = *reinterpret_cast<const float4*>(&X[lane][c4 * 4]);
#pragma unroll
            for (int d = 0; d < 16; ++d) {
                const float4 wv = *reinterpret_cast<const float4*>(qwh + d * 64 + c4 * 4);
                q[d] += xv.x * wv.x + xv.y * wv.y + xv.z * wv.z + xv.w * wv.w;
            }
        }
        float mn0 = msk[lane];
#pragma unroll
        for (int d = 0; d < 16; ++d) q[d] = (q[d] * mn0 + qb[h * 16 + d]) * 0.25f;
    }

    // ---- coop K/V: thread computes channel co=lane for tokens t = h*16+tt
    {
        float ak[16], av[16];
#pragma unroll
        for (int tt = 0; tt < 16; ++tt) { ak[tt] = 0.f; av[tt] = 0.f; }
        const float4* kw4 = reinterpret_cast<const float4*>(kw + lane * 64);
        const float4* vw4 = reinterpret_cast<const float4*>(vw + lane * 64);
        for (int c4 = 0; c4 < 16; ++c4) {
            float4 wk = kw4[c4], wv = vw4[c4];
#pragma unroll
            for (int tt = 0; tt < 16; ++tt) {
                int t = h * 16 + tt;
                float4 yv = *reinterpret_cast<const float4*>(&Y[t][c4 * 4]);
                ak[tt] += yv.x * wk.x + yv.y * wk.y + yv.z * wk.z + yv.w * wk.w;
                av[tt] += yv.x * wv.x + yv.y * wv.y + yv.z * wv.z + yv.w * wv.w;
            }
        }
        float kbv = kb[lane], vbv = vb[lane];
        int co_h = lane >> 4, co_d = lane & 15;
#pragma unroll
        for (int tt = 0; tt < 16; ++tt) {
            int t = h * 16 + tt;
            Kl[co_h][t][co_d] = ak[tt] + kbv;
            Vl[co_h][t][co_d] = av[tt] + vbv;
        }
    }
    __syncthreads();

    // ---- attention scores
    const int i1 = lane >> 3, j1 = lane & 7;
    const float mn = msk[lane];
    float p[64];
#pragma unroll
    for (int m = 0; m < 64; ++m) {
        float s = 0.f;
#pragma unroll
        for (int d4 = 0; d4 < 4; ++d4) {
            float4 kv = *reinterpret_cast<const float4*>(&Kl[h][m][d4 * 4]);
            s += q[d4 * 4 + 0] * kv.x + q[d4 * 4 + 1] * kv.y
               + q[d4 * 4 + 2] * kv.z + q[d4 * 4 + 3] * kv.w;
        }
        int bidx = (i1 - (m >> 3) + 7) * 15 + (j1 - (m & 7) + 7);
        p[m] = s * mn * msk[m] + bl[bidx * 4 + h];
    }
    float mx = p[0];
#pragma unroll
    for (int m = 1; m < 64; ++m) mx = fmaxf(mx, p[m]);
    float sum = 0.f;
#pragma unroll
    for (int m = 0; m < 64; ++m) { p[m] = __expf(p[m] - mx); sum += p[m]; }
    float inv = 1.f / sum;
#pragma unroll
    for (int m = 0; m < 64; ++m) p[m] *= inv;

    // ---- head-mean attention (into Y region; Y dead after proj)
    if (attm) {
        for (int turn = 0; turn < 4; ++turn) {
            if (h == turn) {
                if (turn == 0) {
#pragma unroll
                    for (int m = 0; m < 64; ++m) AMa[m][lane] = p[m] * 0.25f;
                } else {
#pragma unroll
                    for (int m = 0; m < 64; ++m) AMa[m][lane] += p[m] * 0.25f;
                }
            }
            __syncthreads();
        }
        float* ap = attm + ((size_t)bb * nWin + win) * 4096;
        for (int r = tid; r < 4096; r += 256) ap[r] = AMa[r >> 6][r & 63];
        __syncthreads();
    }

    // ---- PV
    float acc[16];
#pragma unroll
    for (int d = 0; d < 16; ++d) acc[d] = 0.f;
#pragma unroll
    for (int m = 0; m < 64; ++m) {
        float pm = p[m];
#pragma unroll
        for (int d4 = 0; d4 < 4; ++d4) {
            float4 vv = *reinterpret_cast<const float4*>(&Vl[h][m][d4 * 4]);
            acc[d4 * 4 + 0] += pm * vv.x; acc[d4 * 4 + 1] += pm * vv.y;
            acc[d4 * 4 + 2] += pm * vv.z; acc[d4 * 4 + 3] += pm * vv.w;
        }
    }
#pragma unroll
    for (int d = 0; d < 16; ++d) X[lane][h * 16 + d] = acc[d];
    __syncthreads();

    // ---- output projection
    {
        float o[16];
        float pbv = pb[lane];
#pragma unroll
        for (int tt = 0; tt < 16; ++tt) o[tt] = pbv;
        const float4* pw4 = reinterpret_cast<const float4*>(pw + lane * 64);
        for (int c4 = 0; c4 < 16; ++c4) {
            float4 w = pw4[c4];
#pragma unroll
            for (int tt = 0; tt < 16; ++tt) {
                int t = h * 16 + tt;
                float4 ov = *reinterpret_cast<const float4*>(&X[t][c4 * 4]);
                o[tt] += ov.x * w.x + ov.y * w.y + ov.z * w.z + ov.w * w.w;
            }
        }
#pragma unroll
        for (int tt = 0; tt < 16; ++tt) AMo[lane][h * 16 + tt] = o[tt];
    }
    __syncthreads();
    // scatter to NHWC bf16: consecutive lanes -> consecutive c (128B segments)
    const size_t obase = (size_t)bb * HW * 64;
    for (int r = tid; r < 4096; r += 256) {
        int c = r & 63, t = r >> 6;
        aligned[obase + ((size_t)(y0 + (t >> 3)) * H + (x0 + (t & 7))) * 64 + c]
            = __float2bfloat16(AMo[c][t]);
    }
}

// ---------------------------------------------------------------------------
// atrans NHWC bf16: out[b,Y,X,c] = sum_{mi,mj} attm[b,win,t(Y,X),mi*8+mj] * ta[b,c,...]
// Block = [1 Y][64 X][64 c]; lane = X (coalesced ta rows), LDS-transposed store.
__global__ __launch_bounds__(256) void atttrans_kernel(const float* __restrict__ ta,
                                                       const float* __restrict__ attm,
                                                       __hip_bfloat16* __restrict__ outw,
                                                       int H, int HW, int nWx16, int nWinAtt) {
    __shared__ float T[64][66];
    const int tid = threadIdx.x;
    const int x = tid & 63;
    const int cq = tid >> 6;
    const int x0 = blockIdx.x * 64;
    const int Y = blockIdx.y;
    const int b = blockIdx.z;
    const int X = x0 + x;
    const int wh = Y >> 4, ww = X >> 4;
    const int win = wh * nWx16 + ww;
    const int t = ((Y & 15) >> 1) * 8 + ((X & 15) >> 1);
    const float* ap = attm + (((size_t)b * nWinAtt + win) * 64 + t) * 64;
    const float* tp = ta + ((size_t)b * 64 + cq * 16) * HW
                         + (size_t)((wh << 4) + (Y & 1)) * H + (ww << 4) + (X & 1);
    float acc[16];
#pragma unroll
    for (int cc = 0; cc < 16; ++cc) acc[cc] = 0.f;
    for (int mi = 0; mi < 8; ++mi) {
#pragma unroll
        for (int mj = 0; mj < 8; ++mj) {
            float a = ap[mi * 8 + mj];
            const float* tb = tp + (size_t)(mi * 2) * H + mj * 2;
#pragma unroll
            for (int cc = 0; cc < 16; ++cc)
                acc[cc] = fmaf(a, tb[(size_t)cc * HW], acc[cc]);
        }
    }
#pragma unroll
    for (int cc = 0; cc < 16; ++cc) T[x][cq * 16 + cc] = acc[cc];
    __syncthreads();
    for (int s = tid; s < 512; s += 256) {
        int xx = s >> 3, oct = s & 7;
        short8 o;
#pragma unroll
        for (int k = 0; k < 8; ++k) o[k] = f2bfbits(T[xx][oct * 8 + k]);
        *reinterpret_cast<short8*>(
            outw + (((size_t)b * H + Y) * H + x0 + xx) * 64 + oct * 8) = o;
    }
}

// ---------------------------------------------------------------------------
// Weight transform into MFMA A-fragment layout, hi/lo bf16 split:
// WH/WL[kykx][chunk][oct][co][j] = split(fc_w[co][ci=chunk*32+oct*8+j][ky][kx])
__global__ __launch_bounds__(256) void wtrans_kernel(const float* __restrict__ src,
                                                     __hip_bfloat16* __restrict__ WH,
                                                     __hip_bfloat16* __restrict__ WL) {
    int idx = blockIdx.x * 256 + threadIdx.x;   // 110592 total
    int j = idx & 7;
    int t1 = idx >> 3;
    int co = t1 & 63;
    int t2 = t1 >> 6;
    int oct = t2 & 3;
    int t3 = t2 >> 2;
    int chunk = t3 % 6;
    int kykx = t3 / 6;
    int ci = chunk * 32 + oct * 8 + j;
    int ky = kykx / 3, kx = kykx % 3;
    float v = src[((co * 192 + ci) * 3 + ky) * 3 + kx];
    __hip_bfloat16 h = __float2bfloat16(v);
    WH[idx] = h;
    WL[idx] = __float2bfloat16(v - __bfloat162float(h));
}

// ---------------------------------------------------------------------------
// MFMA implicit-GEMM 3x3 SAME conv, 192->64 ch, NHWC bf16 in.
// Block = [64 co][4 y][64 x]; wave = one y row holding all 64 co.
// 9 shifted GEMMs (ky,kx) x 6 K-chunks of 32 ci; W split hi/lo (2 mfma/tile).
__global__ __launch_bounds__(256) void conv_mfma_kernel(
    const __hip_bfloat16* __restrict__ s0, const __hip_bfloat16* __restrict__ s1,
    const __hip_bfloat16* __restrict__ s2,
    const __hip_bfloat16* __restrict__ WHp, const __hip_bfloat16* __restrict__ WLp,
    const float* __restrict__ bias,
    float* __restrict__ out,
    int H, int HW, int mode)   // mode 0: NCHW f32 + lrelu (lvl0); 1: NHWC f32 (lvl1)
{
    __shared__ short I[6][66][40];   // rows | x (halo) | ci (pad 40 -> 80B stride, 16B-aligned b128)

    const int tid = threadIdx.x;
    const int w   = tid >> 6;        // wave = y offset in tile
    const int l   = tid & 63;
    const int lq  = l >> 4;
    const int lm  = l & 15;
    const int x0  = blockIdx.x * 64;
    const int y0  = blockIdx.y * 4;
    const size_t zoff = (size_t)blockIdx.z * HW * 64;

    f32x4 acc[4][4];
#pragma unroll
    for (int mt = 0; mt < 4; ++mt)
#pragma unroll
        for (int nt = 0; nt < 4; ++nt) acc[mt][nt] = (f32x4){0.f, 0.f, 0.f, 0.f};

    const short8* WH8 = reinterpret_cast<const short8*>(WHp);
    const short8* WL8 = reinterpret_cast<const short8*>(WLp);

    for (int chunk = 0; chunk < 6; ++chunk) {
        __syncthreads();
        const unsigned short* src = reinterpret_cast<const unsigned short*>(
            (chunk < 2) ? s0 : (chunk < 4) ? s1 : s2);
        const int cib = (chunk & 1) * 32;
        for (int s = tid; s < 1584; s += 256) {        // 6 rows x 66 x x 4 octs
            int oct = s & 3;
            int xr = s >> 2;
            int xi = xr % 66;
            int r = xr / 66;
            int gx = x0 - 1 + xi, gy = y0 - 1 + r;
            short8 v = (short8){0, 0, 0, 0, 0, 0, 0, 0};
            if (gx >= 0 && gx < H && gy >= 0 && gy < H)
                v = *reinterpret_cast<const short8*>(
                        src + zoff + ((size_t)gy * H + gx) * 64 + cib + oct * 8);
            *reinterpret_cast<short8*>(&I[r][xi][oct * 8]) = v;
        }
        __syncthreads();

#pragma unroll
        for (int kk = 0; kk < 9; ++kk) {
            const int ky = kk / 3, kx = kk % 3;
            const int wbase = ((kk * 6 + chunk) * 4 + lq) * 64 + lm;
            short8 ah[4], al[4];
#pragma unroll
            for (int mt = 0; mt < 4; ++mt) {
                ah[mt] = WH8[wbase + mt * 16];
                al[mt] = WL8[wbase + mt * 16];
            }
#pragma unroll
            for (int nt = 0; nt < 4; ++nt) {
                short8 bfrag = *reinterpret_cast<const short8*>(
                                   &I[w + ky][nt * 16 + lm + kx][lq * 8]);
#pragma unroll
                for (int mt = 0; mt < 4; ++mt) {
                    acc[mt][nt] = __builtin_amdgcn_mfma_f32_16x16x32_bf16(
                        ah[mt], bfrag, acc[mt][nt], 0, 0, 0);
                    acc[mt][nt] = __builtin_amdgcn_mfma_f32_16x16x32_bf16(
                        al[mt], bfrag, acc[mt][nt], 0, 0, 0);
                }
            }
        }
    }

    // epilogue: C lane mapping col=lm (x), row=lq*4+r (co within 16-tile)
    const int y = y0 + w;
#pragma unroll
    for (int mt = 0; mt < 4; ++mt) {
#pragma unroll
        for (int r = 0; r < 4; ++r) {
            const int co = mt * 16 + lq * 4 + r;
            const float bv = bias[co];
#pragma unroll
            for (int nt = 0; nt < 4; ++nt) {
                float v = acc[mt][nt][r] + bv;
                const int x = x0 + nt * 16 + lm;
                if (mode == 0) {
                    v = LRELU(v);
                    out[zoff + (size_t)co * HW + (size_t)y * H + x] = v;
                } else {
                    out[zoff + ((size_t)y * H + x) * 64 + co] = v;
                }
            }
        }
    }
}

// ---------------------------------------------------------------------------
// 2x bilinear upsample of lrelu(in); NHWC in (f32 or bf16), NHWC bf16 out.
template <typename T>
__global__ __launch_bounds__(256) void upsample_kernel(const T* __restrict__ in,
                                                       __hip_bfloat16* __restrict__ out,
                                                       int Hin, int total) {
    int idx = blockIdx.x * 256 + threadIdx.x;
    if (idx >= total) return;
    int c = idx & 63;
    int r1 = idx >> 6;
    int W2 = Hin * 2;
    int X = r1 % W2;
    int r2 = r1 / W2;
    int Y = r2 % W2;
    int b = r2 / W2;
    int y0 = Y >> 1, x0 = X >> 1;
    int ya = (Y & 1) ? y0 + 1 : y0 - 1;
    int xa = (X & 1) ? x0 + 1 : x0 - 1;
    ya = ya < 0 ? 0 : (ya >= Hin ? Hin - 1 : ya);
    xa = xa < 0 ? 0 : (xa >= Hin ? Hin - 1 : xa);
    const T* p = in + (size_t)b * Hin * Hin * 64;
    float v00 = LRELU(loadf(p + ((size_t)y0 * Hin + x0) * 64 + c));
    float v01 = LRELU(loadf(p + ((size_t)y0 * Hin + xa) * 64 + c));
    float v10 = LRELU(loadf(p + ((size_t)ya * Hin + x0) * 64 + c));
    float v11 = LRELU(loadf(p + ((size_t)ya * Hin + xa) * 64 + c));
    out[idx] = __float2bfloat16(0.5625f * v00 + 0.1875f * (v01 + v10) + 0.0625f * v11);
}

// ---------------------------------------------------------------------------
extern "C" void kernel_launch(void* const* d_in, const int* in_sizes, int n_in,
                              void* d_out, int out_size, void* d_ws, size_t ws_size,
                              hipStream_t stream) {
    const float* refs[3] = { (const float*)d_in[0], (const float*)d_in[1], (const float*)d_in[2] };
    const float* tas[3]  = { (const float*)d_in[3], (const float*)d_in[4], (const float*)d_in[5] };
    const float* q_w = (const float*)d_in[6];
    const float* q_b = (const float*)d_in[7];
    const float* k_w = (const float*)d_in[8];
    const float* k_b = (const float*)d_in[9];
    const float* v_w = (const float*)d_in[10];
    const float* v_b = (const float*)d_in[11];
    const float* p_w = (const float*)d_in[12];
    const float* p_b = (const float*)d_in[13];
    const float* btab = (const float*)d_in[14];
    const float* fc_w = (const float*)d_in[15];
    const float* fc_b = (const float*)d_in[16];

    // NB=4 needs ~101.5 MB ws (same as round-5's proven budget) + d_out scratch.
    const size_t NB4_NEED = 4ull * 221184 + 3ull * 4 * 65536 * 64 * 2 + 4096;
    const int NB = (ws_size >= NB4_NEED) ? 4 : 1;

    char* p = (char*)d_ws;
    __hip_bfloat16* WH0 = (__hip_bfloat16*)p;  p += 221184;
    __hip_bfloat16* WL0 = (__hip_bfloat16*)p;  p += 221184;
    __hip_bfloat16* WH1 = (__hip_bfloat16*)p;  p += 221184;
    __hip_bfloat16* WL1 = (__hip_bfloat16*)p;  p += 221184;
    __hip_bfloat16* ALIGNED = (__hip_bfloat16*)p;  p += (size_t)NB * 65536 * 64 * 2;
    __hip_bfloat16* UPS     = (__hip_bfloat16*)p;  p += (size_t)NB * 65536 * 64 * 2;
    __hip_bfloat16* ATRANS  = (__hip_bfloat16*)p;  p += (size_t)NB * 65536 * 64 * 2;
    float *ATTMA, *ATTMB, *FEAT2;
    if (NB == 4) {
        // d_out as scratch: all regions consumed before the final conv writes d_out
        ATTMA = (float*)d_out;                     // 4*64*4096   = 1,048,576 f
        ATTMB = (float*)d_out + 1048576;           // 4*256*4096  = 4,194,304 f
        FEAT2 = (float*)d_out + 5242880;           // 4*16384*64  = 4,194,304 f (NHWC)
    } else {
        ATTMA = (float*)p;  p += (size_t)64 * 4096 * 4;
        ATTMB = (float*)p;  p += (size_t)256 * 4096 * 4;
        FEAT2 = (float*)p;  p += (size_t)16384 * 64 * 4;
    }

    wtrans_kernel<<<432, 256, 0, stream>>>(fc_w, WH0, WL0);
    wtrans_kernel<<<432, 256, 0, stream>>>(fc_w + 110592, WH1, WL1);

    for (int b0 = 0; b0 < 4; b0 += NB) {
        const float* ref1 = refs[0] + (size_t)b0 * 64 * 65536;
        const float* ta1  = tas[0]  + (size_t)b0 * 64 * 65536;
        const float* ref2 = refs[1] + (size_t)b0 * 64 * 16384;
        const float* ta2  = tas[1]  + (size_t)b0 * 64 * 16384;
        const float* ref3 = refs[2] + (size_t)b0 * 64 * 4096;
        const float* ta3  = tas[2]  + (size_t)b0 * 64 * 4096;

        // ---- level j=2 (H=64, nWin=64)
        fused_attn_kernel<<<dim3(64, NB), 256, 0, stream>>>(
            ref3, ta3, q_w + 2*4096, q_b + 2*64, k_w + 2*4096, k_b + 2*64,
            v_w + 2*4096, v_b + 2*64, p_w + 2*4096, p_b + 2*64,
            btab + 2*900, ALIGNED, ATTMA, 64, 8, 64);
        upsample_kernel<__hip_bfloat16><<<(NB * 64 * 16384) / 256, 256, 0, stream>>>(
            ALIGNED, UPS, 64, NB * 64 * 16384);

        // ---- level j=1 (H=128, nWin=256)
        fused_attn_kernel<<<dim3(256, NB), 256, 0, stream>>>(
            ref2, ta2, q_w + 4096, q_b + 64, k_w + 4096, k_b + 64,
            v_w + 4096, v_b + 64, p_w + 4096, p_b + 64,
            btab + 900, ALIGNED, ATTMB, 128, 16, 256);
        atttrans_kernel<<<dim3(2, 128, NB), 256, 0, stream>>>(
            ta2, ATTMA, ATRANS, 128, 16384, 8, 64);
        conv_mfma_kernel<<<dim3(2, 32, NB), 256, 0, stream>>>(
            ALIGNED, UPS, ATRANS, WH1, WL1, fc_b + 64, FEAT2, 128, 16384, 1);
        upsample_kernel<float><<<(NB * 64 * 65536) / 256, 256, 0, stream>>>(
            FEAT2, UPS, 128, NB * 64 * 65536);

        // ---- level j=0 (H=256, nWin=1024)
        fused_attn_kernel<<<dim3(1024, NB), 256, 0, stream>>>(
            ref1, ta1, q_w, q_b, k_w, k_b, v_w, v_b, p_w, p_b,
            btab, ALIGNED, nullptr, 256, 32, 1024);
        atttrans_kernel<<<dim3(4, 256, NB), 256, 0, stream>>>(
            ta1, ATTMB, ATRANS, 256, 65536, 16, 256);
        conv_mfma_kernel<<<dim3(4, 64, NB), 256, 0, stream>>>(
            ALIGNED, UPS, ATRANS, WH0, WL0, fc_b,
            (float*)d_out + (size_t)b0 * 64 * 65536, 256, 65536, 0);
    }
}

// Round 7
// 732.301 us; speedup vs baseline: 26.0924x; 1.7544x over previous
//
#include <hip/hip_runtime.h>
#include <hip/hip_bf16.h>
#include <math.h>

#define LRELU(v) ((v) >= 0.f ? (v) : 0.1f * (v))

typedef __attribute__((ext_vector_type(8))) short short8;
typedef __attribute__((ext_vector_type(4))) float f32x4;

#define MFMA16 __builtin_amdgcn_mfma_f32_16x16x32_bf16

__device__ __forceinline__ float loadf(const float* p) { return *p; }
__device__ __forceinline__ float loadf(const __hip_bfloat16* p) { return __bfloat162float(*p); }
__device__ __forceinline__ short f2bfbits(float f) {
    __hip_bfloat16 h = __float2bfloat16(f);
    return *reinterpret_cast<short*>(&h);
}

// split 8 f32 into bf16 hi + residual-lo fragments
__device__ __forceinline__ void split8(const float* s, short8& h8, short8& l8) {
    float4 a = *reinterpret_cast<const float4*>(s);
    float4 b = *reinterpret_cast<const float4*>(s + 4);
    float v[8] = { a.x, a.y, a.z, a.w, b.x, b.y, b.z, b.w };
#pragma unroll
    for (int i = 0; i < 8; ++i) {
        __hip_bfloat16 hb = __float2bfloat16(v[i]);
        h8[i] = *reinterpret_cast<short*>(&hb);
        __hip_bfloat16 lb = __float2bfloat16(v[i] - __bfloat162float(hb));
        l8[i] = *reinterpret_cast<short*>(&lb);
    }
}

// 3-term hi/lo product accumulate (~f32 accuracy)
__device__ __forceinline__ f32x4 mm3(short8 ah, short8 al, short8 bh, short8 bl, f32x4 c) {
    c = MFMA16(ah, bh, c, 0, 0, 0);
    c = MFMA16(ah, bl, c, 0, 0, 0);
    c = MFMA16(al, bh, c, 0, 0, 0);
    return c;
}

// XOR-swizzled index for K / V^T bf16 planes [64 rows][64 cols] (short units)
__device__ __forceinline__ int kidx(int row, int col) {
    return row * 64 + (col ^ ((row & 7) << 3));
}

// ---------------------------------------------------------------------------
// Fused per-window cross attention, full-MFMA. Block = one 8x8 window.
// grid.x = nWin, grid.y = NB. 4 waves; wave w owns token rows 16w..16w+15.
__global__ __launch_bounds__(256) void fused_attn_kernel(
    const float* __restrict__ ref,   // [NB][64][H][H] NCHW f32
    const float* __restrict__ ta,
    const __hip_bfloat16* __restrict__ WQ,  // [2 hl][64 co][64 ci] bf16
    const __hip_bfloat16* __restrict__ WK,
    const __hip_bfloat16* __restrict__ WV,
    const __hip_bfloat16* __restrict__ WP,
    const float* __restrict__ qb, const float* __restrict__ kb,
    const float* __restrict__ vb, const float* __restrict__ pb,
    const float* __restrict__ btab,  // [225][4]
    __hip_bfloat16* __restrict__ aligned,  // [NB][H][H][64] NHWC bf16
    float* __restrict__ attm,        // [NB][nWin][64][64] head-mean attn (q-major), or null
    int H, int nWx, int nWin)
{
    __shared__ float XY[2][64][40];          // staged ci-half of X,Y f32 (aliased by AMp)
    __shared__ short KH[4096], KL[4096];     // K  [tok][d] hi/lo, XOR-swizzled
    __shared__ short VTH[4096], VTL[4096];   // V^T [d][tok] hi/lo, XOR-swizzled
    __shared__ float SCR[4][4][16][20];      // per-wave C-layout -> A-frag transposer
    __shared__ float bl[900];
    __shared__ float msk[64];
    __shared__ float partial[4][64];
    float (*AMp)[80] = reinterpret_cast<float(*)[80]>(&XY[0][0][0]);  // [64 q][80] alias

    const int HW = H * H;
    const int win = blockIdx.x;
    const int bb = blockIdx.y;
    const int wy = win / nWx, wx = win - wy * nWx;
    const int y0 = wy * 8, x0 = wx * 8;
    const int tid = threadIdx.x;
    const int w = __builtin_amdgcn_readfirstlane(tid >> 6);
    const int l = tid & 63;
    const int lq = l >> 4, lm = l & 15;
    const size_t bbase = (size_t)bb * 64 * HW;

    for (int r = tid; r < 900; r += 256) bl[r] = btab[r];

    // ---- phase A: Q/K/V projection GEMMs over 2 ci-halves
    f32x4 aq[4], ak[4], av[4];
#pragma unroll
    for (int nt = 0; nt < 4; ++nt) {
        aq[nt] = (f32x4){0.f, 0.f, 0.f, 0.f};
        ak[nt] = (f32x4){0.f, 0.f, 0.f, 0.f};
        av[nt] = (f32x4){0.f, 0.f, 0.f, 0.f};
    }
    float cnt = 0.f;

    for (int stage = 0; stage < 2; ++stage) {
        if (stage) __syncthreads();          // protect XY overwrite
#pragma unroll
        for (int k = 0; k < 16; ++k) {
            int r = tid + k * 256;
            int tok = r & 63;
            int rest = r >> 6;               // 0..63
            int ci = rest & 31;
            int which = rest >> 5;           // 0:X(ref) 1:Y(ta)
            const float* src = which ? ta : ref;
            float v = src[bbase + (size_t)(stage * 32 + ci) * HW
                          + (size_t)(y0 + (tok >> 3)) * H + (x0 + (tok & 7))];
            XY[which][tok][ci] = v;
            if (!which) cnt += (v > 0.95f) ? 0.f : 1.f;
        }
        __syncthreads();

        // A-frags: rows 16w+lm, ci slice lq*8 (within stage)
        short8 xh, xl, yh, yl;
        split8(&XY[0][16 * w + lm][lq * 8], xh, xl);
        split8(&XY[1][16 * w + lm][lq * 8], yh, yl);

#pragma unroll
        for (int nt = 0; nt < 4; ++nt) {
            const int co = nt * 16 + lm;
            const int cio = stage * 32 + lq * 8;
            short8 bqh = *reinterpret_cast<const short8*>(WQ + co * 64 + cio);
            short8 bql = *reinterpret_cast<const short8*>(WQ + 4096 + co * 64 + cio);
            aq[nt] = mm3(xh, xl, bqh, bql, aq[nt]);
            short8 bkh = *reinterpret_cast<const short8*>(WK + co * 64 + cio);
            short8 bkl = *reinterpret_cast<const short8*>(WK + 4096 + co * 64 + cio);
            ak[nt] = mm3(yh, yl, bkh, bkl, ak[nt]);
            short8 bvh = *reinterpret_cast<const short8*>(WV + co * 64 + cio);
            short8 bvl = *reinterpret_cast<const short8*>(WV + 4096 + co * 64 + cio);
            av[nt] = mm3(yh, yl, bvh, bvl, av[nt]);
        }
    }

    // ---- mask (exact, from f32)
    partial[w][l] = cnt;
    __syncthreads();
    if (tid < 64)
        msk[tid] = (partial[0][tid] + partial[1][tid] + partial[2][tid] + partial[3][tid])
                   * (1.f / 64.f);
    __syncthreads();

    // ---- epilogues: Q in regs (mask row-scale commutes), K/V^T to planes
    float mq[4];
#pragma unroll
    for (int r = 0; r < 4; ++r) mq[r] = msk[16 * w + lq * 4 + r];
#pragma unroll
    for (int nt = 0; nt < 4; ++nt) {
        const int co = nt * 16 + lm;
        float qbv = qb[co], kbv = kb[co], vbv = vb[co];
#pragma unroll
        for (int r = 0; r < 4; ++r) {
            aq[nt][r] = (aq[nt][r] * mq[r] + qbv) * 0.25f;
            int tok = 16 * w + lq * 4 + r;
            float kf = ak[nt][r] + kbv;
            __hip_bfloat16 kh = __float2bfloat16(kf);
            KH[kidx(tok, co)] = *reinterpret_cast<short*>(&kh);
            KL[kidx(tok, co)] = f2bfbits(kf - __bfloat162float(kh));
            float vf = av[nt][r] + vbv;
            __hip_bfloat16 vh = __float2bfloat16(vf);
            VTH[kidx(co, tok)] = *reinterpret_cast<short*>(&vh);
            VTL[kidx(co, tok)] = f2bfbits(vf - __bfloat162float(vh));
        }
    }
    __syncthreads();   // planes visible to all waves; XY now dead (AMp may alias)

    // ---- heads loop: scores -> softmax -> (attm accum) -> PV
    const short8 zero8 = (short8){0, 0, 0, 0, 0, 0, 0, 0};
    f32x4 oacc[4];
#pragma unroll
    for (int h = 0; h < 4; ++h) {
        // stage Q tile (cols 16h..16h+15) and read A-frag (K=16 padded to 32)
#pragma unroll
        for (int r = 0; r < 4; ++r) SCR[w][0][lq * 4 + r][lm] = aq[h][r];
        short8 qah = zero8, qal = zero8;
        if (lq < 2) split8(&SCR[w][0][lm][lq * 8], qah, qal);

        f32x4 s[4];
#pragma unroll
        for (int nt = 0; nt < 4; ++nt) {
            s[nt] = (f32x4){0.f, 0.f, 0.f, 0.f};
            short8 kbh = zero8, kbl = zero8;
            if (lq < 2) {
                int row = nt * 16 + lm;          // k-token
                int cb = h * 16 + lq * 8;        // d
                kbh = *reinterpret_cast<const short8*>(&KH[kidx(row, cb)]);
                kbl = *reinterpret_cast<const short8*>(&KL[kidx(row, cb)]);
            }
            s[nt] = mm3(qah, qal, kbh, kbl, s[nt]);
        }

        // mask + bias
        float p[4][4];   // [r][nt]
#pragma unroll
        for (int nt = 0; nt < 4; ++nt) {
            int kt = nt * 16 + lm;
            float mk = msk[kt];
            int i2 = kt >> 3, j2 = kt & 7;
#pragma unroll
            for (int r = 0; r < 4; ++r) {
                int qt = 16 * w + lq * 4 + r;
                int bidx = ((qt >> 3) - i2 + 7) * 15 + ((qt & 7) - j2 + 7);
                p[r][nt] = s[nt][r] * mq[r] * mk + bl[bidx * 4 + h];
            }
        }
        // row softmax: row (lq,r) spread over nt regs x 16 lm-lanes
#pragma unroll
        for (int r = 0; r < 4; ++r) {
            float mx = fmaxf(fmaxf(p[r][0], p[r][1]), fmaxf(p[r][2], p[r][3]));
            mx = fmaxf(mx, __shfl_xor(mx, 1));
            mx = fmaxf(mx, __shfl_xor(mx, 2));
            mx = fmaxf(mx, __shfl_xor(mx, 4));
            mx = fmaxf(mx, __shfl_xor(mx, 8));
            float sum = 0.f;
#pragma unroll
            for (int nt = 0; nt < 4; ++nt) { p[r][nt] = __expf(p[r][nt] - mx); sum += p[r][nt]; }
            sum += __shfl_xor(sum, 1);
            sum += __shfl_xor(sum, 2);
            sum += __shfl_xor(sum, 4);
            sum += __shfl_xor(sum, 8);
            float inv = 1.f / sum;
#pragma unroll
            for (int nt = 0; nt < 4; ++nt) p[r][nt] *= inv;
        }

        // head-mean attention, q-major (wave-exclusive rows; no barrier needed)
        if (attm) {
#pragma unroll
            for (int nt = 0; nt < 4; ++nt)
#pragma unroll
                for (int r = 0; r < 4; ++r) {
                    int qt = 16 * w + lq * 4 + r, kt = nt * 16 + lm;
                    if (h == 0) AMp[qt][kt] = p[r][nt] * 0.25f;
                    else        AMp[qt][kt] += p[r][nt] * 0.25f;
                }
        }

        // PV: stage P tiles, A-frag rows lm, k = tok
#pragma unroll
        for (int nt = 0; nt < 4; ++nt)
#pragma unroll
            for (int r = 0; r < 4; ++r) SCR[w][nt][lq * 4 + r][lm] = p[r][nt];
        f32x4 o = (f32x4){0.f, 0.f, 0.f, 0.f};
#pragma unroll
        for (int kk = 0; kk < 2; ++kk) {
            short8 pah, pal;
            split8(&SCR[w][kk * 2 + (lq >> 1)][lm][(lq & 1) * 8], pah, pal);
            int vrow = 16 * h + lm;              // d
            int vcb = kk * 32 + lq * 8;          // tok
            short8 vbh = *reinterpret_cast<const short8*>(&VTH[kidx(vrow, vcb)]);
            short8 vbl = *reinterpret_cast<const short8*>(&VTL[kidx(vrow, vcb)]);
            o = mm3(pah, pal, vbh, vbl, o);
        }
        oacc[h] = o;   // O[q=16w+lq*4+r][d=16h+lm]
    }

    if (attm) {
        __syncthreads();
        float* ap = attm + ((size_t)bb * nWin + win) * 4096;
        for (int r = tid; r < 1024; r += 256) {
            const float* s = &AMp[r >> 4][(r & 15) * 4];
            *reinterpret_cast<float4*>(ap + r * 4) = make_float4(s[0], s[1], s[2], s[3]);
        }
    }

    // ---- phase E: out-projection O[64][64] @ Wp^T
#pragma unroll
    for (int h = 0; h < 4; ++h)
#pragma unroll
        for (int r = 0; r < 4; ++r) SCR[w][h][lq * 4 + r][lm] = oacc[h][r];
    f32x4 eo[4];
#pragma unroll
    for (int nt = 0; nt < 4; ++nt) eo[nt] = (f32x4){0.f, 0.f, 0.f, 0.f};
#pragma unroll
    for (int kk = 0; kk < 2; ++kk) {
        short8 oah, oal;
        split8(&SCR[w][kk * 2 + (lq >> 1)][lm][(lq & 1) * 8], oah, oal);
#pragma unroll
        for (int nt = 0; nt < 4; ++nt) {
            const int co = nt * 16 + lm;
            const int cio = kk * 32 + lq * 8;
            short8 wbh = *reinterpret_cast<const short8*>(WP + co * 64 + cio);
            short8 wbl = *reinterpret_cast<const short8*>(WP + 4096 + co * 64 + cio);
            eo[nt] = mm3(oah, oal, wbh, wbl, eo[nt]);
        }
    }
    const size_t obase = (size_t)bb * HW * 64;
#pragma unroll
    for (int nt = 0; nt < 4; ++nt) {
        float pbv = pb[nt * 16 + lm];
#pragma unroll
        for (int r = 0; r < 4; ++r) {
            int tok = 16 * w + lq * 4 + r;
            aligned[obase + ((size_t)(y0 + (tok >> 3)) * H + (x0 + (tok & 7))) * 64
                    + nt * 16 + lm] = __float2bfloat16(eo[nt][r] + pbv);
        }
    }
}

// ---------------------------------------------------------------------------
// Attn-weight hi/lo split: dst[(j*4+mat)*8192 + {0,4096} + co*64+ci]
__global__ __launch_bounds__(256) void wsplit_kernel(const float* __restrict__ qw,
                                                     const float* __restrict__ kw,
                                                     const float* __restrict__ vw,
                                                     const float* __restrict__ pw,
                                                     __hip_bfloat16* __restrict__ dst) {
    int idx = blockIdx.x * 256 + threadIdx.x;   // 49152 total
    int e = idx & 4095;
    int mat = (idx >> 12) & 3;
    int j = idx >> 14;
    const float* src = (mat == 0 ? qw : mat == 1 ? kw : mat == 2 ? vw : pw) + j * 4096;
    float v = src[e];
    __hip_bfloat16 h = __float2bfloat16(v);
    dst[((size_t)j * 4 + mat) * 8192 + e] = h;
    dst[((size_t)j * 4 + mat) * 8192 + 4096 + e] = __float2bfloat16(v - __bfloat162float(h));
}

// ---------------------------------------------------------------------------
// atrans NHWC bf16 (unchanged from R6)
__global__ __launch_bounds__(256) void atttrans_kernel(const float* __restrict__ ta,
                                                       const float* __restrict__ attm,
                                                       __hip_bfloat16* __restrict__ outw,
                                                       int H, int HW, int nWx16, int nWinAtt) {
    __shared__ float T[64][66];
    const int tid = threadIdx.x;
    const int x = tid & 63;
    const int cq = tid >> 6;
    const int x0 = blockIdx.x * 64;
    const int Y = blockIdx.y;
    const int b = blockIdx.z;
    const int X = x0 + x;
    const int wh = Y >> 4, ww = X >> 4;
    const int win = wh * nWx16 + ww;
    const int t = ((Y & 15) >> 1) * 8 + ((X & 15) >> 1);
    const float* ap = attm + (((size_t)b * nWinAtt + win) * 64 + t) * 64;
    const float* tp = ta + ((size_t)b * 64 + cq * 16) * HW
                         + (size_t)((wh << 4) + (Y & 1)) * H + (ww << 4) + (X & 1);
    float acc[16];
#pragma unroll
    for (int cc = 0; cc < 16; ++cc) acc[cc] = 0.f;
    for (int mi = 0; mi < 8; ++mi) {
#pragma unroll
        for (int mj = 0; mj < 8; ++mj) {
            float a = ap[mi * 8 + mj];
            const float* tb = tp + (size_t)(mi * 2) * H + mj * 2;
#pragma unroll
            for (int cc = 0; cc < 16; ++cc)
                acc[cc] = fmaf(a, tb[(size_t)cc * HW], acc[cc]);
        }
    }
#pragma unroll
    for (int cc = 0; cc < 16; ++cc) T[x][cq * 16 + cc] = acc[cc];
    __syncthreads();
    for (int s = tid; s < 512; s += 256) {
        int xx = s >> 3, oct = s & 7;
        short8 o;
#pragma unroll
        for (int k = 0; k < 8; ++k) o[k] = f2bfbits(T[xx][oct * 8 + k]);
        *reinterpret_cast<short8*>(
            outw + (((size_t)b * H + Y) * H + x0 + xx) * 64 + oct * 8) = o;
    }
}

// ---------------------------------------------------------------------------
// Conv weight transform (unchanged from R6)
__global__ __launch_bounds__(256) void wtrans_kernel(const float* __restrict__ src,
                                                     __hip_bfloat16* __restrict__ WH,
                                                     __hip_bfloat16* __restrict__ WL) {
    int idx = blockIdx.x * 256 + threadIdx.x;   // 110592 total
    int j = idx & 7;
    int t1 = idx >> 3;
    int co = t1 & 63;
    int t2 = t1 >> 6;
    int oct = t2 & 3;
    int t3 = t2 >> 2;
    int chunk = t3 % 6;
    int kykx = t3 / 6;
    int ci = chunk * 32 + oct * 8 + j;
    int ky = kykx / 3, kx = kykx % 3;
    float v = src[((co * 192 + ci) * 3 + ky) * 3 + kx];
    __hip_bfloat16 h = __float2bfloat16(v);
    WH[idx] = h;
    WL[idx] = __float2bfloat16(v - __bfloat162float(h));
}

// ---------------------------------------------------------------------------
// MFMA implicit-GEMM 3x3 conv (unchanged from R6)
__global__ __launch_bounds__(256) void conv_mfma_kernel(
    const __hip_bfloat16* __restrict__ s0, const __hip_bfloat16* __restrict__ s1,
    const __hip_bfloat16* __restrict__ s2,
    const __hip_bfloat16* __restrict__ WHp, const __hip_bfloat16* __restrict__ WLp,
    const float* __restrict__ bias,
    float* __restrict__ out,
    int H, int HW, int mode)
{
    __shared__ short I[6][66][40];

    const int tid = threadIdx.x;
    const int w   = tid >> 6;
    const int l   = tid & 63;
    const int lq  = l >> 4;
    const int lm  = l & 15;
    const int x0  = blockIdx.x * 64;
    const int y0  = blockIdx.y * 4;
    const size_t zoff = (size_t)blockIdx.z * HW * 64;

    f32x4 acc[4][4];
#pragma unroll
    for (int mt = 0; mt < 4; ++mt)
#pragma unroll
        for (int nt = 0; nt < 4; ++nt) acc[mt][nt] = (f32x4){0.f, 0.f, 0.f, 0.f};

    const short8* WH8 = reinterpret_cast<const short8*>(WHp);
    const short8* WL8 = reinterpret_cast<const short8*>(WLp);

    for (int chunk = 0; chunk < 6; ++chunk) {
        __syncthreads();
        const unsigned short* src = reinterpret_cast<const unsigned short*>(
            (chunk < 2) ? s0 : (chunk < 4) ? s1 : s2);
        const int cib = (chunk & 1) * 32;
        for (int s = tid; s < 1584; s += 256) {
            int oct = s & 3;
            int xr = s >> 2;
            int xi = xr % 66;
            int r = xr / 66;
            int gx = x0 - 1 + xi, gy = y0 - 1 + r;
            short8 v = (short8){0, 0, 0, 0, 0, 0, 0, 0};
            if (gx >= 0 && gx < H && gy >= 0 && gy < H)
                v = *reinterpret_cast<const short8*>(
                        src + zoff + ((size_t)gy * H + gx) * 64 + cib + oct * 8);
            *reinterpret_cast<short8*>(&I[r][xi][oct * 8]) = v;
        }
        __syncthreads();

#pragma unroll
        for (int kk = 0; kk < 9; ++kk) {
            const int ky = kk / 3, kx = kk % 3;
            const int wbase = ((kk * 6 + chunk) * 4 + lq) * 64 + lm;
            short8 ah[4], al[4];
#pragma unroll
            for (int mt = 0; mt < 4; ++mt) {
                ah[mt] = WH8[wbase + mt * 16];
                al[mt] = WL8[wbase + mt * 16];
            }
#pragma unroll
            for (int nt = 0; nt < 4; ++nt) {
                short8 bfrag = *reinterpret_cast<const short8*>(
                                   &I[w + ky][nt * 16 + lm + kx][lq * 8]);
#pragma unroll
                for (int mt = 0; mt < 4; ++mt) {
                    acc[mt][nt] = MFMA16(ah[mt], bfrag, acc[mt][nt], 0, 0, 0);
                    acc[mt][nt] = MFMA16(al[mt], bfrag, acc[mt][nt], 0, 0, 0);
                }
            }
        }
    }

    const int y = y0 + w;
#pragma unroll
    for (int mt = 0; mt < 4; ++mt) {
#pragma unroll
        for (int r = 0; r < 4; ++r) {
            const int co = mt * 16 + lq * 4 + r;
            const float bv = bias[co];
#pragma unroll
            for (int nt = 0; nt < 4; ++nt) {
                float v = acc[mt][nt][r] + bv;
                const int x = x0 + nt * 16 + lm;
                if (mode == 0) {
                    v = LRELU(v);
                    out[zoff + (size_t)co * HW + (size_t)y * H + x] = v;
                } else {
                    out[zoff + ((size_t)y * H + x) * 64 + co] = v;
                }
            }
        }
    }
}

// ---------------------------------------------------------------------------
// 2x bilinear upsample of lrelu(in); NHWC (unchanged from R6)
template <typename T>
__global__ __launch_bounds__(256) void upsample_kernel(const T* __restrict__ in,
                                                       __hip_bfloat16* __restrict__ out,
                                                       int Hin, int total) {
    int idx = blockIdx.x * 256 + threadIdx.x;
    if (idx >= total) return;
    int c = idx & 63;
    int r1 = idx >> 6;
    int W2 = Hin * 2;
    int X = r1 % W2;
    int r2 = r1 / W2;
    int Y = r2 % W2;
    int b = r2 / W2;
    int y0 = Y >> 1, x0 = X >> 1;
    int ya = (Y & 1) ? y0 + 1 : y0 - 1;
    int xa = (X & 1) ? x0 + 1 : x0 - 1;
    ya = ya < 0 ? 0 : (ya >= Hin ? Hin - 1 : ya);
    xa = xa < 0 ? 0 : (xa >= Hin ? Hin - 1 : xa);
    const T* p = in + (size_t)b * Hin * Hin * 64;
    float v00 = LRELU(loadf(p + ((size_t)y0 * Hin + x0) * 64 + c));
    float v01 = LRELU(loadf(p + ((size_t)y0 * Hin + xa) * 64 + c));
    float v10 = LRELU(loadf(p + ((size_t)ya * Hin + x0) * 64 + c));
    float v11 = LRELU(loadf(p + ((size_t)ya * Hin + xa) * 64 + c));
    out[idx] = __float2bfloat16(0.5625f * v00 + 0.1875f * (v01 + v10) + 0.0625f * v11);
}

// ---------------------------------------------------------------------------
extern "C" void kernel_launch(void* const* d_in, const int* in_sizes, int n_in,
                              void* d_out, int out_size, void* d_ws, size_t ws_size,
                              hipStream_t stream) {
    const float* refs[3] = { (const float*)d_in[0], (const float*)d_in[1], (const float*)d_in[2] };
    const float* tas[3]  = { (const float*)d_in[3], (const float*)d_in[4], (const float*)d_in[5] };
    const float* q_w = (const float*)d_in[6];
    const float* q_b = (const float*)d_in[7];
    const float* k_w = (const float*)d_in[8];
    const float* k_b = (const float*)d_in[9];
    const float* v_w = (const float*)d_in[10];
    const float* v_b = (const float*)d_in[11];
    const float* p_w = (const float*)d_in[12];
    const float* p_b = (const float*)d_in[13];
    const float* btab = (const float*)d_in[14];
    const float* fc_w = (const float*)d_in[15];
    const float* fc_b = (const float*)d_in[16];

    const size_t NB4_NEED = 4ull * 221184 + 196608 + 3ull * 4 * 65536 * 64 * 2 + 4096;
    const int NB = (ws_size >= NB4_NEED) ? 4 : 1;

    char* p = (char*)d_ws;
    __hip_bfloat16* WH0 = (__hip_bfloat16*)p;  p += 221184;
    __hip_bfloat16* WL0 = (__hip_bfloat16*)p;  p += 221184;
    __hip_bfloat16* WH1 = (__hip_bfloat16*)p;  p += 221184;
    __hip_bfloat16* WL1 = (__hip_bfloat16*)p;  p += 221184;
    __hip_bfloat16* WTA = (__hip_bfloat16*)p;  p += 196608;   // 3 lvl x 4 mats x hi/lo
    __hip_bfloat16* ALIGNED = (__hip_bfloat16*)p;  p += (size_t)NB * 65536 * 64 * 2;
    __hip_bfloat16* UPS     = (__hip_bfloat16*)p;  p += (size_t)NB * 65536 * 64 * 2;
    __hip_bfloat16* ATRANS  = (__hip_bfloat16*)p;  p += (size_t)NB * 65536 * 64 * 2;
    float *ATTMA, *ATTMB, *FEAT2;
    if (NB == 4) {
        ATTMA = (float*)d_out;                     // d_out scratch, dead before final conv
        ATTMB = (float*)d_out + 1048576;
        FEAT2 = (float*)d_out + 5242880;
    } else {
        ATTMA = (float*)p;  p += (size_t)64 * 4096 * 4;
        ATTMB = (float*)p;  p += (size_t)256 * 4096 * 4;
        FEAT2 = (float*)p;  p += (size_t)16384 * 64 * 4;
    }

    wtrans_kernel<<<432, 256, 0, stream>>>(fc_w, WH0, WL0);
    wtrans_kernel<<<432, 256, 0, stream>>>(fc_w + 110592, WH1, WL1);
    wsplit_kernel<<<192, 256, 0, stream>>>(q_w, k_w, v_w, p_w, WTA);

    for (int b0 = 0; b0 < 4; b0 += NB) {
        const float* ref1 = refs[0] + (size_t)b0 * 64 * 65536;
        const float* ta1  = tas[0]  + (size_t)b0 * 64 * 65536;
        const float* ref2 = refs[1] + (size_t)b0 * 64 * 16384;
        const float* ta2  = tas[1]  + (size_t)b0 * 64 * 16384;
        const float* ref3 = refs[2] + (size_t)b0 * 64 * 4096;
        const float* ta3  = tas[2]  + (size_t)b0 * 64 * 4096;

        // ---- level j=2 (H=64, nWin=64)
        fused_attn_kernel<<<dim3(64, NB), 256, 0, stream>>>(
            ref3, ta3,
            WTA + (2*4+0)*8192, WTA + (2*4+1)*8192, WTA + (2*4+2)*8192, WTA + (2*4+3)*8192,
            q_b + 2*64, k_b + 2*64, v_b + 2*64, p_b + 2*64,
            btab + 2*900, ALIGNED, ATTMA, 64, 8, 64);
        upsample_kernel<__hip_bfloat16><<<(NB * 64 * 16384) / 256, 256, 0, stream>>>(
            ALIGNED, UPS, 64, NB * 64 * 16384);

        // ---- level j=1 (H=128, nWin=256)
        fused_attn_kernel<<<dim3(256, NB), 256, 0, stream>>>(
            ref2, ta2,
            WTA + (1*4+0)*8192, WTA + (1*4+1)*8192, WTA + (1*4+2)*8192, WTA + (1*4+3)*8192,
            q_b + 64, k_b + 64, v_b + 64, p_b + 64,
            btab + 900, ALIGNED, ATTMB, 128, 16, 256);
        atttrans_kernel<<<dim3(2, 128, NB), 256, 0, stream>>>(
            ta2, ATTMA, ATRANS, 128, 16384, 8, 64);
        conv_mfma_kernel<<<dim3(2, 32, NB), 256, 0, stream>>>(
            ALIGNED, UPS, ATRANS, WH1, WL1, fc_b + 64, FEAT2, 128, 16384, 1);
        upsample_kernel<float><<<(NB * 64 * 65536) / 256, 256, 0, stream>>>(
            FEAT2, UPS, 128, NB * 64 * 65536);

        // ---- level j=0 (H=256, nWin=1024)
        fused_attn_kernel<<<dim3(1024, NB), 256, 0, stream>>>(
            ref1, ta1,
            WTA + 0*8192, WTA + 1*8192, WTA + 2*8192, WTA + 3*8192,
            q_b, k_b, v_b, p_b,
            btab, ALIGNED, nullptr, 256, 32, 1024);
        atttrans_kernel<<<dim3(4, 256, NB), 256, 0, stream>>>(
            ta1, ATTMB, ATRANS, 256, 65536, 16, 256);
        conv_mfma_kernel<<<dim3(4, 64, NB), 256, 0, stream>>>(
            ALIGNED, UPS, ATRANS, WH0, WL0, fc_b,
            (float*)d_out + (size_t)b0 * 64 * 65536, 256, 65536, 0);
    }
}

// Round 8
// 671.331 us; speedup vs baseline: 28.4621x; 1.0908x over previous
//
#include <hip/hip_runtime.h>
#include <hip/hip_bf16.h>
#include <math.h>

#define LRELU(v) ((v) >= 0.f ? (v) : 0.1f * (v))

typedef __attribute__((ext_vector_type(8))) short short8;
typedef __attribute__((ext_vector_type(4))) float f32x4;

#define MFMA16 __builtin_amdgcn_mfma_f32_16x16x32_bf16

__device__ __forceinline__ float loadf(const float* p) { return *p; }
__device__ __forceinline__ float loadf(const __hip_bfloat16* p) { return __bfloat162float(*p); }
__device__ __forceinline__ short f2bfbits(float f) {
    __hip_bfloat16 h = __float2bfloat16(f);
    return *reinterpret_cast<short*>(&h);
}
__device__ __forceinline__ float bits2f(unsigned short u) {
    union { unsigned int i; float f; } x; x.i = ((unsigned int)u) << 16; return x.f;
}

// 8 scalar f32 LDS reads -> bf16x8 fragment
__device__ __forceinline__ short8 ld_bf8(const float* s) {
    short8 o;
#pragma unroll
    for (int i = 0; i < 8; ++i) o[i] = f2bfbits(s[i]);
    return o;
}

// ---------------------------------------------------------------------------
// Fused per-window cross attention, full-MFMA, 39.97 KB LDS (4 blocks/CU).
// Block = one 8x8 window; 4 waves; wave w owns token rows 16w..16w+15 in
// every GEMM (M-dim), so P/O/Q planes are wave-private by row.
__global__ __launch_bounds__(256, 4) void fused_attn_kernel(
    const float* __restrict__ ref,   // [NB][64][H][H] NCHW f32
    const float* __restrict__ ta,
    const __hip_bfloat16* __restrict__ WQ,  // [2 hl][64 co][64 ci] bf16
    const __hip_bfloat16* __restrict__ WK,
    const __hip_bfloat16* __restrict__ WV,
    const __hip_bfloat16* __restrict__ WP,
    const float* __restrict__ qb, const float* __restrict__ kb,
    const float* __restrict__ vb, const float* __restrict__ pb,
    const float* __restrict__ btab,  // [225][4]
    __hip_bfloat16* __restrict__ aligned,  // [NB][H][H][64] NHWC bf16
    float* __restrict__ attm,        // [NB][nWin][64][64] head-mean attn (q-major), or null
    int H, int nWx, int nWin)
{
    __shared__ __align__(16) char SMEM[39968];
    float* XYp = (float*)SMEM;                               // [2][64][33] f32 (phase A)
    unsigned short* QH = (unsigned short*)SMEM;              // [64][72] bf16 (alias XY)
    unsigned short* PP = (unsigned short*)(SMEM + 9216);     // [64][72] bf16 P / O plane
    unsigned short* KH = (unsigned short*)(SMEM + 18432);    // [64 tok][72 d]
    unsigned short* VT = (unsigned short*)(SMEM + 27648);    // [64 d][72 tok]
    unsigned short* BLB = (unsigned short*)(SMEM + 36864);   // 900 bf16 bias table
    float* MSK  = (float*)(SMEM + 38688);                    // 64
    float* PART = (float*)(SMEM + 38944);                    // [4][64]

    const int HW = H * H;
    const int win = blockIdx.x;
    const int bb = blockIdx.y;
    const int wy = win / nWx, wx = win - wy * nWx;
    const int y0 = wy * 8, x0 = wx * 8;
    const int tid = threadIdx.x;
    const int w = __builtin_amdgcn_readfirstlane(tid >> 6);
    const int l = tid & 63;
    const int lq = l >> 4, lm = l & 15;
    const size_t bbase = (size_t)bb * 64 * HW;

    for (int r = tid; r < 900; r += 256) BLB[r] = (unsigned short)f2bfbits(btab[r]);

    // ---- phase A: Q/K/V projection GEMMs over 2 ci-halves (XY stride-33 f32)
    f32x4 aq[4], ak[4], av[4];
#pragma unroll
    for (int nt = 0; nt < 4; ++nt) {
        aq[nt] = (f32x4){0.f, 0.f, 0.f, 0.f};
        ak[nt] = (f32x4){0.f, 0.f, 0.f, 0.f};
        av[nt] = (f32x4){0.f, 0.f, 0.f, 0.f};
    }
    float cnt = 0.f;

    for (int stage = 0; stage < 2; ++stage) {
        if (stage) __syncthreads();          // all stage-0 reads done
#pragma unroll
        for (int k = 0; k < 16; ++k) {
            int r = tid + k * 256;
            int tok = r & 63;
            int rest = r >> 6;               // 0..63
            int ci = rest & 31;
            int which = rest >> 5;           // 0:X(ref) 1:Y(ta)
            const float* src = which ? ta : ref;
            float v = src[bbase + (size_t)(stage * 32 + ci) * HW
                          + (size_t)(y0 + (tok >> 3)) * H + (x0 + (tok & 7))];
            XYp[(which * 64 + tok) * 33 + ci] = v;   // 2-way banks: free
            if (!which) cnt += (v > 0.95f) ? 0.f : 1.f;
        }
        __syncthreads();

        short8 xa = ld_bf8(&XYp[(16 * w + lm) * 33 + lq * 8]);
        short8 ya = ld_bf8(&XYp[(64 + 16 * w + lm) * 33 + lq * 8]);

#pragma unroll
        for (int nt = 0; nt < 4; ++nt) {
            const int co = nt * 16 + lm;
            const int cio = stage * 32 + lq * 8;
            short8 bh = *reinterpret_cast<const short8*>(WQ + co * 64 + cio);
            short8 bl8 = *reinterpret_cast<const short8*>(WQ + 4096 + co * 64 + cio);
            aq[nt] = MFMA16(xa, bh, aq[nt], 0, 0, 0);
            aq[nt] = MFMA16(xa, bl8, aq[nt], 0, 0, 0);
            bh = *reinterpret_cast<const short8*>(WK + co * 64 + cio);
            bl8 = *reinterpret_cast<const short8*>(WK + 4096 + co * 64 + cio);
            ak[nt] = MFMA16(ya, bh, ak[nt], 0, 0, 0);
            ak[nt] = MFMA16(ya, bl8, ak[nt], 0, 0, 0);
            bh = *reinterpret_cast<const short8*>(WV + co * 64 + cio);
            bl8 = *reinterpret_cast<const short8*>(WV + 4096 + co * 64 + cio);
            av[nt] = MFMA16(ya, bh, av[nt], 0, 0, 0);
            av[nt] = MFMA16(ya, bl8, av[nt], 0, 0, 0);
        }
    }

    // ---- mask (exact, from f32)
    PART[w * 64 + l] = cnt;
    __syncthreads();
    if (tid < 64)
        MSK[tid] = (PART[tid] + PART[64 + tid] + PART[128 + tid] + PART[192 + tid])
                   * (1.f / 64.f);
    __syncthreads();   // MSK visible; XY fully dead -> QH/PP may overwrite

    // ---- epilogue: Q (masked+scaled), K, V^T into bf16 planes
    float mq[4];
#pragma unroll
    for (int r = 0; r < 4; ++r) mq[r] = MSK[16 * w + lq * 4 + r];
#pragma unroll
    for (int nt = 0; nt < 4; ++nt) {
        const int co = nt * 16 + lm;
        float qbv = qb[co], kbv = kb[co], vbv = vb[co];
#pragma unroll
        for (int r = 0; r < 4; ++r) {
            int tokr = 16 * w + lq * 4 + r;
            QH[tokr * 72 + co] = (unsigned short)f2bfbits((aq[nt][r] * mq[r] + qbv) * 0.25f);
            KH[tokr * 72 + co] = (unsigned short)f2bfbits(ak[nt][r] + kbv);
            VT[co * 72 + tokr] = (unsigned short)f2bfbits(av[nt][r] + vbv);
        }
    }
    __syncthreads();   // planes visible cross-wave (heads loop is barrier-free)

    // ---- heads loop: scores -> softmax -> attAcc(regs) -> PV
    const short8 z8 = (short8){0, 0, 0, 0, 0, 0, 0, 0};
    const f32x4 zf = (f32x4){0.f, 0.f, 0.f, 0.f};
    float attAcc[4][4];
#pragma unroll
    for (int r = 0; r < 4; ++r)
#pragma unroll
        for (int nt = 0; nt < 4; ++nt) attAcc[r][nt] = 0.f;
    f32x4 oacc[4];

#pragma unroll
    for (int h = 0; h < 4; ++h) {
        short8 qa = z8;
        if (lq < 2) qa = *reinterpret_cast<const short8*>(&QH[(16 * w + lm) * 72 + h * 16 + lq * 8]);
        f32x4 s[4];
#pragma unroll
        for (int nt = 0; nt < 4; ++nt) {
            short8 kb8 = z8;
            if (lq < 2) kb8 = *reinterpret_cast<const short8*>(
                                  &KH[(nt * 16 + lm) * 72 + h * 16 + lq * 8]);
            s[nt] = MFMA16(qa, kb8, zf, 0, 0, 0);
        }

        float p[4][4];   // [r][nt]
#pragma unroll
        for (int nt = 0; nt < 4; ++nt) {
            int kt = nt * 16 + lm;
            float mk = MSK[kt];
            int i2 = kt >> 3, j2 = kt & 7;
#pragma unroll
            for (int r = 0; r < 4; ++r) {
                int qt = 16 * w + lq * 4 + r;
                int bidx = ((qt >> 3) - i2 + 7) * 15 + ((qt & 7) - j2 + 7);
                p[r][nt] = s[nt][r] * mq[r] * mk + bits2f(BLB[bidx * 4 + h]);
            }
        }
#pragma unroll
        for (int r = 0; r < 4; ++r) {
            float mx = fmaxf(fmaxf(p[r][0], p[r][1]), fmaxf(p[r][2], p[r][3]));
            mx = fmaxf(mx, __shfl_xor(mx, 1));
            mx = fmaxf(mx, __shfl_xor(mx, 2));
            mx = fmaxf(mx, __shfl_xor(mx, 4));
            mx = fmaxf(mx, __shfl_xor(mx, 8));
            float sum = 0.f;
#pragma unroll
            for (int nt = 0; nt < 4; ++nt) { p[r][nt] = __expf(p[r][nt] - mx); sum += p[r][nt]; }
            sum += __shfl_xor(sum, 1);
            sum += __shfl_xor(sum, 2);
            sum += __shfl_xor(sum, 4);
            sum += __shfl_xor(sum, 8);
            float inv = 1.f / sum;
#pragma unroll
            for (int nt = 0; nt < 4; ++nt) p[r][nt] *= inv;
        }

        if (attm) {
#pragma unroll
            for (int r = 0; r < 4; ++r)
#pragma unroll
                for (int nt = 0; nt < 4; ++nt) attAcc[r][nt] += 0.25f * p[r][nt];
        }

        // P -> wave-private rows of PP plane (in-order DS ops, no barrier)
#pragma unroll
        for (int nt = 0; nt < 4; ++nt)
#pragma unroll
            for (int r = 0; r < 4; ++r)
                PP[(16 * w + lq * 4 + r) * 72 + nt * 16 + lm] =
                    (unsigned short)f2bfbits(p[r][nt]);

        f32x4 o = zf;
#pragma unroll
        for (int kk = 0; kk < 2; ++kk) {
            short8 pa = *reinterpret_cast<const short8*>(
                            &PP[(16 * w + lm) * 72 + kk * 32 + lq * 8]);
            short8 vb8 = *reinterpret_cast<const short8*>(
                            &VT[(16 * h + lm) * 72 + kk * 32 + lq * 8]);
            o = MFMA16(pa, vb8, o, 0, 0, 0);
        }
        oacc[h] = o;   // O[q=16w+lq*4+r][d=16h+lm]
    }

    if (attm) {
        float* ap = attm + ((size_t)bb * nWin + win) * 4096;
#pragma unroll
        for (int r = 0; r < 4; ++r)
#pragma unroll
            for (int nt = 0; nt < 4; ++nt)
                ap[(16 * w + lq * 4 + r) * 64 + nt * 16 + lm] = attAcc[r][nt];
    }

    // ---- out-projection: O via PP plane (write-after-read, same wave rows)
#pragma unroll
    for (int h = 0; h < 4; ++h)
#pragma unroll
        for (int r = 0; r < 4; ++r)
            PP[(16 * w + lq * 4 + r) * 72 + h * 16 + lm] =
                (unsigned short)f2bfbits(oacc[h][r]);

    f32x4 eo[4];
#pragma unroll
    for (int nt = 0; nt < 4; ++nt) eo[nt] = zf;
#pragma unroll
    for (int kk = 0; kk < 2; ++kk) {
        short8 oa = *reinterpret_cast<const short8*>(
                        &PP[(16 * w + lm) * 72 + kk * 32 + lq * 8]);
#pragma unroll
        for (int nt = 0; nt < 4; ++nt) {
            const int co = nt * 16 + lm;
            const int cio = kk * 32 + lq * 8;
            short8 wbh = *reinterpret_cast<const short8*>(WP + co * 64 + cio);
            short8 wbl = *reinterpret_cast<const short8*>(WP + 4096 + co * 64 + cio);
            eo[nt] = MFMA16(oa, wbh, eo[nt], 0, 0, 0);
            eo[nt] = MFMA16(oa, wbl, eo[nt], 0, 0, 0);
        }
    }
    const size_t obase = (size_t)bb * HW * 64;
#pragma unroll
    for (int nt = 0; nt < 4; ++nt) {
        float pbv = pb[nt * 16 + lm];
#pragma unroll
        for (int r = 0; r < 4; ++r) {
            int tok = 16 * w + lq * 4 + r;
            aligned[obase + ((size_t)(y0 + (tok >> 3)) * H + (x0 + (tok & 7))) * 64
                    + nt * 16 + lm] = __float2bfloat16(eo[nt][r] + pbv);
        }
    }
}

// ---------------------------------------------------------------------------
// Attn-weight hi/lo split: dst[(j*4+mat)*8192 + {0,4096} + co*64+ci]
__global__ __launch_bounds__(256) void wsplit_kernel(const float* __restrict__ qw,
                                                     const float* __restrict__ kw,
                                                     const float* __restrict__ vw,
                                                     const float* __restrict__ pw,
                                                     __hip_bfloat16* __restrict__ dst) {
    int idx = blockIdx.x * 256 + threadIdx.x;   // 49152 total
    int e = idx & 4095;
    int mat = (idx >> 12) & 3;
    int j = idx >> 14;
    const float* src = (mat == 0 ? qw : mat == 1 ? kw : mat == 2 ? vw : pw) + j * 4096;
    float v = src[e];
    __hip_bfloat16 h = __float2bfloat16(v);
    dst[((size_t)j * 4 + mat) * 8192 + e] = h;
    dst[((size_t)j * 4 + mat) * 8192 + 4096 + e] = __float2bfloat16(v - __bfloat162float(h));
}

// ---------------------------------------------------------------------------
// atrans NHWC bf16 (unchanged)
__global__ __launch_bounds__(256) void atttrans_kernel(const float* __restrict__ ta,
                                                       const float* __restrict__ attm,
                                                       __hip_bfloat16* __restrict__ outw,
                                                       int H, int HW, int nWx16, int nWinAtt) {
    __shared__ float T[64][66];
    const int tid = threadIdx.x;
    const int x = tid & 63;
    const int cq = tid >> 6;
    const int x0 = blockIdx.x * 64;
    const int Y = blockIdx.y;
    const int b = blockIdx.z;
    const int X = x0 + x;
    const int wh = Y >> 4, ww = X >> 4;
    const int win = wh * nWx16 + ww;
    const int t = ((Y & 15) >> 1) * 8 + ((X & 15) >> 1);
    const float* ap = attm + (((size_t)b * nWinAtt + win) * 64 + t) * 64;
    const float* tp = ta + ((size_t)b * 64 + cq * 16) * HW
                         + (size_t)((wh << 4) + (Y & 1)) * H + (ww << 4) + (X & 1);
    float acc[16];
#pragma unroll
    for (int cc = 0; cc < 16; ++cc) acc[cc] = 0.f;
    for (int mi = 0; mi < 8; ++mi) {
#pragma unroll
        for (int mj = 0; mj < 8; ++mj) {
            float a = ap[mi * 8 + mj];
            const float* tb = tp + (size_t)(mi * 2) * H + mj * 2;
#pragma unroll
            for (int cc = 0; cc < 16; ++cc)
                acc[cc] = fmaf(a, tb[(size_t)cc * HW], acc[cc]);
        }
    }
#pragma unroll
    for (int cc = 0; cc < 16; ++cc) T[x][cq * 16 + cc] = acc[cc];
    __syncthreads();
    for (int s = tid; s < 512; s += 256) {
        int xx = s >> 3, oct = s & 7;
        short8 o;
#pragma unroll
        for (int k = 0; k < 8; ++k) o[k] = f2bfbits(T[xx][oct * 8 + k]);
        *reinterpret_cast<short8*>(
            outw + (((size_t)b * H + Y) * H + x0 + xx) * 64 + oct * 8) = o;
    }
}

// ---------------------------------------------------------------------------
// Conv weight transform (unchanged)
__global__ __launch_bounds__(256) void wtrans_kernel(const float* __restrict__ src,
                                                     __hip_bfloat16* __restrict__ WH,
                                                     __hip_bfloat16* __restrict__ WL) {
    int idx = blockIdx.x * 256 + threadIdx.x;   // 110592 total
    int j = idx & 7;
    int t1 = idx >> 3;
    int co = t1 & 63;
    int t2 = t1 >> 6;
    int oct = t2 & 3;
    int t3 = t2 >> 2;
    int chunk = t3 % 6;
    int kykx = t3 / 6;
    int ci = chunk * 32 + oct * 8 + j;
    int ky = kykx / 3, kx = kykx % 3;
    float v = src[((co * 192 + ci) * 3 + ky) * 3 + kx];
    __hip_bfloat16 h = __float2bfloat16(v);
    WH[idx] = h;
    WL[idx] = __float2bfloat16(v - __bfloat162float(h));
}

// ---------------------------------------------------------------------------
// MFMA implicit-GEMM 3x3 conv (unchanged)
__global__ __launch_bounds__(256) void conv_mfma_kernel(
    const __hip_bfloat16* __restrict__ s0, const __hip_bfloat16* __restrict__ s1,
    const __hip_bfloat16* __restrict__ s2,
    const __hip_bfloat16* __restrict__ WHp, const __hip_bfloat16* __restrict__ WLp,
    const float* __restrict__ bias,
    float* __restrict__ out,
    int H, int HW, int mode)
{
    __shared__ short I[6][66][40];

    const int tid = threadIdx.x;
    const int w   = tid >> 6;
    const int l   = tid & 63;
    const int lq  = l >> 4;
    const int lm  = l & 15;
    const int x0  = blockIdx.x * 64;
    const int y0  = blockIdx.y * 4;
    const size_t zoff = (size_t)blockIdx.z * HW * 64;

    f32x4 acc[4][4];
#pragma unroll
    for (int mt = 0; mt < 4; ++mt)
#pragma unroll
        for (int nt = 0; nt < 4; ++nt) acc[mt][nt] = (f32x4){0.f, 0.f, 0.f, 0.f};

    const short8* WH8 = reinterpret_cast<const short8*>(WHp);
    const short8* WL8 = reinterpret_cast<const short8*>(WLp);

    for (int chunk = 0; chunk < 6; ++chunk) {
        __syncthreads();
        const unsigned short* src = reinterpret_cast<const unsigned short*>(
            (chunk < 2) ? s0 : (chunk < 4) ? s1 : s2);
        const int cib = (chunk & 1) * 32;
        for (int s = tid; s < 1584; s += 256) {
            int oct = s & 3;
            int xr = s >> 2;
            int xi = xr % 66;
            int r = xr / 66;
            int gx = x0 - 1 + xi, gy = y0 - 1 + r;
            short8 v = (short8){0, 0, 0, 0, 0, 0, 0, 0};
            if (gx >= 0 && gx < H && gy >= 0 && gy < H)
                v = *reinterpret_cast<const short8*>(
                        src + zoff + ((size_t)gy * H + gx) * 64 + cib + oct * 8);
            *reinterpret_cast<short8*>(&I[r][xi][oct * 8]) = v;
        }
        __syncthreads();

#pragma unroll
        for (int kk = 0; kk < 9; ++kk) {
            const int ky = kk / 3, kx = kk % 3;
            const int wbase = ((kk * 6 + chunk) * 4 + lq) * 64 + lm;
            short8 ah[4], al[4];
#pragma unroll
            for (int mt = 0; mt < 4; ++mt) {
                ah[mt] = WH8[wbase + mt * 16];
                al[mt] = WL8[wbase + mt * 16];
            }
#pragma unroll
            for (int nt = 0; nt < 4; ++nt) {
                short8 bfrag = *reinterpret_cast<const short8*>(
                                   &I[w + ky][nt * 16 + lm + kx][lq * 8]);
#pragma unroll
                for (int mt = 0; mt < 4; ++mt) {
                    acc[mt][nt] = MFMA16(ah[mt], bfrag, acc[mt][nt], 0, 0, 0);
                    acc[mt][nt] = MFMA16(al[mt], bfrag, acc[mt][nt], 0, 0, 0);
                }
            }
        }
    }

    const int y = y0 + w;
#pragma unroll
    for (int mt = 0; mt < 4; ++mt) {
#pragma unroll
        for (int r = 0; r < 4; ++r) {
            const int co = mt * 16 + lq * 4 + r;
            const float bv = bias[co];
#pragma unroll
            for (int nt = 0; nt < 4; ++nt) {
                float v = acc[mt][nt][r] + bv;
                const int x = x0 + nt * 16 + lm;
                if (mode == 0) {
                    v = LRELU(v);
                    out[zoff + (size_t)co * HW + (size_t)y * H + x] = v;
                } else {
                    out[zoff + ((size_t)y * H + x) * 64 + co] = v;
                }
            }
        }
    }
}

// ---------------------------------------------------------------------------
// 2x bilinear upsample of lrelu(in); NHWC (unchanged)
template <typename T>
__global__ __launch_bounds__(256) void upsample_kernel(const T* __restrict__ in,
                                                       __hip_bfloat16* __restrict__ out,
                                                       int Hin, int total) {
    int idx = blockIdx.x * 256 + threadIdx.x;
    if (idx >= total) return;
    int c = idx & 63;
    int r1 = idx >> 6;
    int W2 = Hin * 2;
    int X = r1 % W2;
    int r2 = r1 / W2;
    int Y = r2 % W2;
    int b = r2 / W2;
    int y0 = Y >> 1, x0 = X >> 1;
    int ya = (Y & 1) ? y0 + 1 : y0 - 1;
    int xa = (X & 1) ? x0 + 1 : x0 - 1;
    ya = ya < 0 ? 0 : (ya >= Hin ? Hin - 1 : ya);
    xa = xa < 0 ? 0 : (xa >= Hin ? Hin - 1 : xa);
    const T* p = in + (size_t)b * Hin * Hin * 64;
    float v00 = LRELU(loadf(p + ((size_t)y0 * Hin + x0) * 64 + c));
    float v01 = LRELU(loadf(p + ((size_t)y0 * Hin + xa) * 64 + c));
    float v10 = LRELU(loadf(p + ((size_t)ya * Hin + x0) * 64 + c));
    float v11 = LRELU(loadf(p + ((size_t)ya * Hin + xa) * 64 + c));
    out[idx] = __float2bfloat16(0.5625f * v00 + 0.1875f * (v01 + v10) + 0.0625f * v11);
}

// ---------------------------------------------------------------------------
extern "C" void kernel_launch(void* const* d_in, const int* in_sizes, int n_in,
                              void* d_out, int out_size, void* d_ws, size_t ws_size,
                              hipStream_t stream) {
    const float* refs[3] = { (const float*)d_in[0], (const float*)d_in[1], (const float*)d_in[2] };
    const float* tas[3]  = { (const float*)d_in[3], (const float*)d_in[4], (const float*)d_in[5] };
    const float* q_w = (const float*)d_in[6];
    const float* q_b = (const float*)d_in[7];
    const float* k_w = (const float*)d_in[8];
    const float* k_b = (const float*)d_in[9];
    const float* v_w = (const float*)d_in[10];
    const float* v_b = (const float*)d_in[11];
    const float* p_w = (const float*)d_in[12];
    const float* p_b = (const float*)d_in[13];
    const float* btab = (const float*)d_in[14];
    const float* fc_w = (const float*)d_in[15];
    const float* fc_b = (const float*)d_in[16];

    const size_t NB4_NEED = 4ull * 221184 + 196608 + 3ull * 4 * 65536 * 64 * 2 + 4096;
    const int NB = (ws_size >= NB4_NEED) ? 4 : 1;

    char* p = (char*)d_ws;
    __hip_bfloat16* WH0 = (__hip_bfloat16*)p;  p += 221184;
    __hip_bfloat16* WL0 = (__hip_bfloat16*)p;  p += 221184;
    __hip_bfloat16* WH1 = (__hip_bfloat16*)p;  p += 221184;
    __hip_bfloat16* WL1 = (__hip_bfloat16*)p;  p += 221184;
    __hip_bfloat16* WTA = (__hip_bfloat16*)p;  p += 196608;   // 3 lvl x 4 mats x hi/lo
    __hip_bfloat16* ALIGNED = (__hip_bfloat16*)p;  p += (size_t)NB * 65536 * 64 * 2;
    __hip_bfloat16* UPS     = (__hip_bfloat16*)p;  p += (size_t)NB * 65536 * 64 * 2;
    __hip_bfloat16* ATRANS  = (__hip_bfloat16*)p;  p += (size_t)NB * 65536 * 64 * 2;
    float *ATTMA, *ATTMB, *FEAT2;
    if (NB == 4) {
        ATTMA = (float*)d_out;                     // d_out scratch, dead before final conv
        ATTMB = (float*)d_out + 1048576;
        FEAT2 = (float*)d_out + 5242880;
    } else {
        ATTMA = (float*)p;  p += (size_t)64 * 4096 * 4;
        ATTMB = (float*)p;  p += (size_t)256 * 4096 * 4;
        FEAT2 = (float*)p;  p += (size_t)16384 * 64 * 4;
    }

    wtrans_kernel<<<432, 256, 0, stream>>>(fc_w, WH0, WL0);
    wtrans_kernel<<<432, 256, 0, stream>>>(fc_w + 110592, WH1, WL1);
    wsplit_kernel<<<192, 256, 0, stream>>>(q_w, k_w, v_w, p_w, WTA);

    for (int b0 = 0; b0 < 4; b0 += NB) {
        const float* ref1 = refs[0] + (size_t)b0 * 64 * 65536;
        const float* ta1  = tas[0]  + (size_t)b0 * 64 * 65536;
        const float* ref2 = refs[1] + (size_t)b0 * 64 * 16384;
        const float* ta2  = tas[1]  + (size_t)b0 * 64 * 16384;
        const float* ref3 = refs[2] + (size_t)b0 * 64 * 4096;
        const float* ta3  = tas[2]  + (size_t)b0 * 64 * 4096;

        // ---- level j=2 (H=64, nWin=64)
        fused_attn_kernel<<<dim3(64, NB), 256, 0, stream>>>(
            ref3, ta3,
            WTA + (2*4+0)*8192, WTA + (2*4+1)*8192, WTA + (2*4+2)*8192, WTA + (2*4+3)*8192,
            q_b + 2*64, k_b + 2*64, v_b + 2*64, p_b + 2*64,
            btab + 2*900, ALIGNED, ATTMA, 64, 8, 64);
        upsample_kernel<__hip_bfloat16><<<(NB * 64 * 16384) / 256, 256, 0, stream>>>(
            ALIGNED, UPS, 64, NB * 64 * 16384);

        // ---- level j=1 (H=128, nWin=256)
        fused_attn_kernel<<<dim3(256, NB), 256, 0, stream>>>(
            ref2, ta2,
            WTA + (1*4+0)*8192, WTA + (1*4+1)*8192, WTA + (1*4+2)*8192, WTA + (1*4+3)*8192,
            q_b + 64, k_b + 64, v_b + 64, p_b + 64,
            btab + 900, ALIGNED, ATTMB, 128, 16, 256);
        atttrans_kernel<<<dim3(2, 128, NB), 256, 0, stream>>>(
            ta2, ATTMA, ATRANS, 128, 16384, 8, 64);
        conv_mfma_kernel<<<dim3(2, 32, NB), 256, 0, stream>>>(
            ALIGNED, UPS, ATRANS, WH1, WL1, fc_b + 64, FEAT2, 128, 16384, 1);
        upsample_kernel<float><<<(NB * 64 * 65536) / 256, 256, 0, stream>>>(
            FEAT2, UPS, 128, NB * 64 * 65536);

        // ---- level j=0 (H=256, nWin=1024)
        fused_attn_kernel<<<dim3(1024, NB), 256, 0, stream>>>(
            ref1, ta1,
            WTA + 0*8192, WTA + 1*8192, WTA + 2*8192, WTA + 3*8192,
            q_b, k_b, v_b, p_b,
            btab, ALIGNED, nullptr, 256, 32, 1024);
        atttrans_kernel<<<dim3(4, 256, NB), 256, 0, stream>>>(
            ta1, ATTMB, ATRANS, 256, 65536, 16, 256);
        conv_mfma_kernel<<<dim3(4, 64, NB), 256, 0, stream>>>(
            ALIGNED, UPS, ATRANS, WH0, WL0, fc_b,
            (float*)d_out + (size_t)b0 * 64 * 65536, 256, 65536, 0);
    }
}